// Round 8
// baseline (1171.746 us; speedup 1.0000x reference)
//
#include <hip/hip_runtime.h>
#include <math.h>

#define CC 192
#define TTT 768
#define PP 29
#define LOG2PI_F 1.8378770664093453f
#define WSLOT 36864   // swizzled 192x192 slot (elements)
#define PSW 6144      // swizzled 32x192 proj slot (elements)
#define XS 200        // ushort stride for conv_cc/transpose LDS tiles
#define XSF 196       // float stride for mega ping rows (784B, 16B-aligned)

typedef __attribute__((ext_vector_type(8))) short short8;
typedef __attribute__((ext_vector_type(4))) float floatx4;
typedef __attribute__((ext_vector_type(2))) float float2v;
union Frag { int4 i; short8 s; };

__device__ __forceinline__ float2v fma2(float2v a, float2v b, float2v c){
  return __builtin_elementwise_fma(a, b, c);
}
__device__ __forceinline__ float geluf(float x){
  float u = 1.5957691216057308f * (x + 0.044715f*x*x*x);
  return x * __builtin_amdgcn_rcpf(1.f + __expf(-u));
}
__device__ __forceinline__ float softplus_f(float x){
  return (x > 20.f) ? x : log1pf(__expf(x));
}
__device__ __forceinline__ float logsig_f(float x){
  return -softplus_f(-x);
}
__device__ __forceinline__ unsigned short f2bf(float f){
  unsigned int u = __builtin_bit_cast(unsigned int, f);
  u += 0x7fffu + ((u >> 16) & 1u);
  return (unsigned short)(u >> 16);
}
__device__ __forceinline__ unsigned int packbf2(float a0, float a1){
  return (unsigned int)f2bf(a0) | ((unsigned int)f2bf(a1) << 16);
}
__device__ __forceinline__ void unbf2(unsigned int u, float& lo, float& hi){
  lo = __builtin_bit_cast(float, u << 16);
  hi = __builtin_bit_cast(float, u & 0xffff0000u);
}
__device__ __forceinline__ void unp8(int4 v, float* o){
  unsigned int* p = (unsigned int*)&v;
  unbf2(p[0], o[0], o[1]); unbf2(p[1], o[2], o[3]);
  unbf2(p[2], o[4], o[5]); unbf2(p[3], o[6], o[7]);
}
__device__ __forceinline__ void f4arr(float4 v, float* o){ o[0]=v.x;o[1]=v.y;o[2]=v.z;o[3]=v.w; }

// ---------------- weight f32 -> bf16 swizzled fragment order ----------------
__global__ __launch_bounds__(256) void convert_w_k(
    const float* __restrict__ p0, const float* __restrict__ p1,
    const float* __restrict__ p2, const float* __restrict__ p3,
    const float* __restrict__ p4, const float* __restrict__ p5,
    const float* __restrict__ p6, const float* __restrict__ p7,
    const float* __restrict__ p8, unsigned short* __restrict__ Wb){
  int i = blockIdx.x*256 + threadIdx.x;
  const int totalA = 33*WSLOT;
  const int total = totalA + 8*PSW;
  if (i >= total) return;
  if (i < totalA){
    int slot = i / WSLOT, j = i % WSLOT;
    int e = j & 7, lane = (j>>3) & 63, kt = j >> 9;
    int k = kt % 6, tile = kt / 6;
    int co = tile*16 + (lane & 15);
    int kk = k*32 + (lane>>4)*8 + e;
    int r = co*CC + kk;
    const float* src;
    if      (slot == 0) src = p0 + r;
    else if (slot == 1) src = p1 + r;
    else if (slot == 2) src = p2 + r;
    else if (slot < 6)  src = p3 + (size_t)(slot-3)*WSLOT + r;
    else if (slot < 9)  src = p4 + (size_t)(slot-6)*WSLOT + r;
    else if (slot < 21) src = p5 + (size_t)(slot-9)*WSLOT + r;
    else                src = p6 + (size_t)(slot-21)*WSLOT + r;
    Wb[i] = f2bf(*src);
  } else {
    int r2 = i - totalA;
    int ps = r2 / PSW, j = r2 % PSW;
    int e = j & 7, lane = (j>>3) & 63, kt = j >> 9;
    int k = kt % 6, tile = kt / 6;
    int co = tile*16 + (lane & 15); if (co > PP-1) co = PP-1;
    int kk = k*32 + (lane>>4)*8 + e;
    const float* base = (ps < 4) ? (p7 + (size_t)ps*PP*CC) : (p8 + (size_t)(ps-4)*PP*CC);
    Wb[i] = f2bf(base[co*CC + kk]);
  }
}

// ---------------- x f32 [B][C][T] -> bf16 [B][T][C] ----------------
__global__ __launch_bounds__(256) void transpose_x_k(
    const float* __restrict__ x, unsigned short* __restrict__ xT){
  __shared__ unsigned short tile[32*XS];
  int b = blockIdx.y, t0 = blockIdx.x*32, tid = threadIdx.x;
  int tl4 = (tid & 7)*4, cr = tid >> 3;
  #pragma unroll
  for (int rnd=0; rnd<6; rnd++){
    int c = rnd*32 + cr;
    float4 v4 = *(const float4*)(x + ((size_t)b*CC + c)*TTT + t0 + tl4);
    tile[(tl4+0)*XS + c] = f2bf(v4.x);
    tile[(tl4+1)*XS + c] = f2bf(v4.y);
    tile[(tl4+2)*XS + c] = f2bf(v4.z);
    tile[(tl4+3)*XS + c] = f2bf(v4.w);
  }
  __syncthreads();
  #pragma unroll
  for (int k=0;k<3;k++){
    int task = k*256 + tid;
    int row = task/24, cn = task%24;
    *(int4*)(xT + ((size_t)b*TTT + t0 + row)*CC + cn*8) = *(const int4*)&tile[row*XS + cn*8];
  }
}

// ---------------- conv 192x192 bf16 MFMA, t-major bf16 in/out ----------------
__global__ __launch_bounds__(256) void conv_cc_k(
    const unsigned short* __restrict__ in, const unsigned short* __restrict__ Wsw,
    const float* __restrict__ bias, const float* __restrict__ mask,
    const unsigned short* __restrict__ addsrc, unsigned short* __restrict__ outb, int mode){
  __shared__ unsigned short bufX[32*XS];
  __shared__ unsigned short bufY[32*XS];
  __shared__ float marr[32];
  int b = blockIdx.y, t0 = blockIdx.x*32, tid = threadIdx.x;
  #pragma unroll
  for (int k=0;k<3;k++){
    int task = k*256 + tid;
    int row = task/24, cn = task%24;
    const unsigned short* src = in + ((size_t)b*TTT + t0 + row)*CC + cn*8;
    *(int4*)&bufX[row*XS + cn*8] = *(const int4*)src;
    if (mode == 2){
      const unsigned short* s2 = addsrc + ((size_t)b*TTT + t0 + row)*CC + cn*8;
      *(int4*)&bufY[row*XS + cn*8] = *(const int4*)s2;
    }
  }
  if (tid >= 128 && tid < 160) marr[tid-128] = mask[(size_t)b*TTT + t0 + (tid-128)];
  __syncthreads();
  int w = tid >> 6, lane = tid & 63;
  int n16 = lane & 15, quad = lane >> 4;
  Frag af[3][6];
  #pragma unroll
  for (int ct=0; ct<3; ct++){
    int tile = w*3 + ct;
    #pragma unroll
    for (int k=0;k<6;k++)
      af[ct][k].i = *(const int4*)(Wsw + ((size_t)(tile*6 + k)*64 + lane)*8);
  }
  floatx4 acc[3][2];
  #pragma unroll
  for (int ct=0;ct<3;ct++)
    #pragma unroll
    for (int tt=0;tt<2;tt++)
      acc[ct][tt] = (floatx4){0.f,0.f,0.f,0.f};
  #pragma unroll
  for (int k=0;k<6;k++){
    Frag bf[2];
    #pragma unroll
    for (int tt=0;tt<2;tt++)
      bf[tt].i = *(const int4*)&bufX[(tt*16+n16)*XS + k*32 + quad*8];
    #pragma unroll
    for (int ct=0;ct<3;ct++)
      #pragma unroll
      for (int tt=0;tt<2;tt++)
        acc[ct][tt] = __builtin_amdgcn_mfma_f32_16x16x32_bf16(af[ct][k].s, bf[tt].s, acc[ct][tt], 0,0,0);
  }
  __syncthreads();
  #pragma unroll
  for (int ct=0;ct<3;ct++){
    int cobase = w*48 + ct*16 + quad*4;
    float4 b4 = *(const float4*)(bias + cobase);
    float ba[4] = {b4.x, b4.y, b4.z, b4.w};
    #pragma unroll
    for (int tt=0;tt<2;tt++){
      int t = tt*16 + n16;
      float mv = (mode >= 1) ? marr[t] : 1.f;
      float av[4] = {0.f,0.f,0.f,0.f};
      if (mode == 2){
        uint2 uy = *(uint2*)&bufY[t*XS + cobase];
        unbf2(uy.x, av[0], av[1]); unbf2(uy.y, av[2], av[3]);
      }
      float hh[4];
      #pragma unroll
      for (int r=0;r<4;r++){
        float v = acc[ct][tt][r] + ba[r];
        if (mode >= 1) v *= mv;
        if (mode == 2) v += av[r];
        hh[r] = v;
      }
      uint2 wv; wv.x = packbf2(hh[0], hh[1]); wv.y = packbf2(hh[2], hh[3]);
      *(uint2*)&bufX[t*XS + cobase] = wv;
    }
  }
  __syncthreads();
  #pragma unroll
  for (int k=0;k<3;k++){
    int task = k*256 + tid;
    int row = task/24, cn = task%24;
    *(int4*)(outb + ((size_t)b*TTT + t0 + row)*CC + cn*8) = *(const int4*)&bufX[row*XS + cn*8];
  }
}

// ---------------- mega DDS v3: f32 ping, wave-per-t-tile, B-frags in registers ----------------
__global__ __launch_bounds__(256,3) void mega_dds_k(
    const unsigned short* __restrict__ in,
    const float* __restrict__ zsrc, int zstride,
    const unsigned short* __restrict__ g,
    unsigned short* __restrict__ outb,
    const float* __restrict__ mask,
    const float* __restrict__ dwB, const float* __restrict__ dbB,
    const float* __restrict__ lngB, const float* __restrict__ lnbB,
    const float* __restrict__ pwbB,
    const float* __restrict__ pw1, const float* __restrict__ pb1,
    const unsigned short* __restrict__ Wsw,
    int srcmode, int outmode,
    const unsigned short* __restrict__ projW, const float* __restrict__ projB,
    float* __restrict__ z, int zs, float* __restrict__ acco){
  __shared__ float ping[64*XSF];   // f32 [window row][c], in-place residual stream
  __shared__ float mrow[64];
  __shared__ float pro[32*30];

  int b = blockIdx.y, t0 = blockIdx.x*32, tid = threadIdx.x;
  int ws0 = t0 - 16;
  int w = tid >> 6, lane = tid & 63;
  int n16 = lane & 15, quad = lane >> 4;
  int row = w*16 + n16;                      // this lane's window row
  const float* mkb = mask + (size_t)b*TTT;
  const int dils[3] = {1,3,9};

  if (tid < 64){
    int gt = ws0 + tid;
    bool inr = (gt >= 0) && (gt < TTT);
    int gc = gt < 0 ? 0 : (gt > TTT-1 ? TTT-1 : gt);
    mrow[tid] = inr ? mkb[gc] : 0.f;
  }
  // ---- staging (pre-masked, f32) ----
  if (srcmode == 0){
    #pragma unroll
    for (int k=0;k<6;k++){
      int task = k*256 + tid;
      int r = task/24, cn = task%24, c0 = cn*8;
      int gt = ws0 + r;
      bool inr = (gt >= 0) && (gt < TTT);
      int gc = gt < 0 ? 0 : (gt > TTT-1 ? TTT-1 : gt);
      float mv = inr ? mkb[gc] : 0.f;
      float hv[8];
      unp8(*(const int4*)(in + ((size_t)b*TTT + gc)*CC + c0), hv);
      float4 o0 = make_float4(hv[0]*mv, hv[1]*mv, hv[2]*mv, hv[3]*mv);
      float4 o1 = make_float4(hv[4]*mv, hv[5]*mv, hv[6]*mv, hv[7]*mv);
      *(float4*)&ping[r*XSF + c0]     = o0;
      *(float4*)&ping[r*XSF + c0 + 4] = o1;
    }
  } else {
    #pragma unroll
    for (int k=0;k<6;k++){
      int task = k*256 + tid;
      int r = task/24, cn = task%24, c0 = cn*8;
      int gt = ws0 + r;
      bool inr = (gt >= 0) && (gt < TTT);
      int gc = gt < 0 ? 0 : (gt > TTT-1 ? TTT-1 : gt);
      float mv = inr ? mkb[gc] : 0.f;
      float zv = inr ? zsrc[(size_t)b*zstride + gc] : 0.f;
      float hv[8];
      if (g){
        unp8(*(const int4*)(g + ((size_t)b*TTT + gc)*CC + c0), hv);
      } else {
        #pragma unroll
        for (int e=0;e<8;e++) hv[e] = 0.f;
      }
      float4 pwa = *(const float4*)(pw1 + c0);
      float4 pwb2 = *(const float4*)(pw1 + c0 + 4);
      float4 pba = *(const float4*)(pb1 + c0);
      float4 pbb2 = *(const float4*)(pb1 + c0 + 4);
      float pwv[8], pbv[8];
      f4arr(pwa, pwv); f4arr(pwb2, pwv+4);
      f4arr(pba, pbv); f4arr(pbb2, pbv+4);
      float ov[8];
      #pragma unroll
      for (int e=0;e<8;e++) ov[e] = (hv[e] + fmaf(pwv[e], zv, pbv[e]))*mv;
      *(float4*)&ping[r*XSF + c0]     = make_float4(ov[0],ov[1],ov[2],ov[3]);
      *(float4*)&ping[r*XSF + c0 + 4] = make_float4(ov[4],ov[5],ov[6],ov[7]);
    }
  }
  __syncthreads();

  // ---- 3 fused layers ----
  #pragma unroll
  for (int l=0; l<3; l++){
    const int dil = dils[l];
    const bool active = (l < 2) || (w == 1) || (w == 2);
    Frag bfr[6];
    floatx4 acc[12];
    if (active){
      int iL = row - dil; iL = iL < 0 ? 0 : iL;
      int iR = row + dil; iR = iR > 63 ? 63 : iR;
      const float* dwl = dwB + l*CC*3;
      const float* dbl = dbB + l*CC;
      float ml = (row - dil >= 0) ? mrow[iL] : 0.f;
      float mc = mrow[row];
      float mr = (row + dil <= 63) ? mrow[iR] : 0.f;
      float2v ml2 = {ml,ml}, mc2 = {mc,mc}, mr2 = {mr,mr};
      float2v vv[24];
      float s = 0.f, q = 0.f;
      #pragma unroll
      for (int j=0;j<6;j++){
        int kk = j*32 + quad*8;
        float XL[8], XC[8], XR[8];
        f4arr(*(const float4*)&ping[iL*XSF + kk], XL);
        f4arr(*(const float4*)&ping[iL*XSF + kk + 4], XL+4);
        f4arr(*(const float4*)&ping[row*XSF + kk], XC);
        f4arr(*(const float4*)&ping[row*XSF + kk + 4], XC+4);
        f4arr(*(const float4*)&ping[iR*XSF + kk], XR);
        f4arr(*(const float4*)&ping[iR*XSF + kk + 4], XR+4);
        #pragma unroll
        for (int p=0;p<4;p++){
          int cc = kk + 2*p;
          float2v w0 = {dwl[cc*3+0], dwl[cc*3+3]};
          float2v w1 = {dwl[cc*3+1], dwl[cc*3+4]};
          float2v w2 = {dwl[cc*3+2], dwl[cc*3+5]};
          float2v bb = {dbl[cc], dbl[cc+1]};
          float2v xl = {XL[2*p], XL[2*p+1]};
          float2v xc = {XC[2*p], XC[2*p+1]};
          float2v xr = {XR[2*p], XR[2*p+1]};
          float2v val = fma2(w0, xl*ml2, fma2(w1, xc*mc2, fma2(w2, xr*mr2, bb)));
          vv[j*4+p] = val;
          s += val.x + val.y;
          q = fmaf(val.x, val.x, fmaf(val.y, val.y, q));
        }
      }
      s += __shfl_xor(s, 16); s += __shfl_xor(s, 32);
      q += __shfl_xor(q, 16); q += __shfl_xor(q, 32);
      float mm = s*(1.f/CC);
      float rr = rsqrtf(q*(1.f/CC) - mm*mm + 1e-5f);
      // P3: LN + gelu -> B fragments in registers
      {
        const float* g0p = lngB + (l*2)*CC;
        const float* b0p = lnbB + (l*2)*CC;
        float2v mm2 = {mm,mm}, rr2 = {rr,rr};
        #pragma unroll
        for (int j=0;j<6;j++){
          int kk = j*32 + quad*8;
          unsigned int wwp[4];
          #pragma unroll
          for (int p=0;p<4;p++){
            int cc = kk + 2*p;
            float2v a = fma2((vv[j*4+p]-mm2)*rr2, (float2v){g0p[cc], g0p[cc+1]},
                             (float2v){b0p[cc], b0p[cc+1]});
            wwp[p] = packbf2(geluf(a.x), geluf(a.y));
          }
          bfr[j].i = make_int4((int)wwp[0], (int)wwp[1], (int)wwp[2], (int)wwp[3]);
        }
      }
    }
    __syncthreads();   // all P1 ping reads done before in-place P6 writes
    if (active){
      // P4: stream all 12 A-tiles, B from registers
      const unsigned short* WL = Wsw + (size_t)l*WSLOT;
      #pragma unroll
      for (int tile=0; tile<12; tile++){
        acc[tile] = (floatx4){0.f,0.f,0.f,0.f};
        Frag af[6];
        #pragma unroll
        for (int k=0;k<6;k++)
          af[k].i = *(const int4*)(WL + ((size_t)(tile*6 + k)*64 + lane)*8);
        #pragma unroll
        for (int k=0;k<6;k++)
          acc[tile] = __builtin_amdgcn_mfma_f32_16x16x32_bf16(af[k].s, bfr[k].s, acc[tile], 0,0,0);
      }
      // bias + conv-LN stats (in-wave)
      const float* pbp = pwbB + l*CC;
      float s2 = 0.f, q2 = 0.f;
      #pragma unroll
      for (int tile=0; tile<12; tile++){
        int co = tile*16 + quad*4;
        float4 pbv = *(const float4*)(pbp + co);
        float pba[4]; f4arr(pbv, pba);
        #pragma unroll
        for (int r=0;r<4;r++){
          acc[tile][r] += pba[r];
          float x = acc[tile][r];
          s2 += x; q2 = fmaf(x, x, q2);
        }
      }
      s2 += __shfl_xor(s2, 16); s2 += __shfl_xor(s2, 32);
      q2 += __shfl_xor(q2, 16); q2 += __shfl_xor(q2, 32);
      float cmP = s2*(1.f/CC);
      float crP = rsqrtf(q2*(1.f/CC) - cmP*cmP + 1e-5f);
      // P6: LN + gelu + residual, in-place f32 (each 16B owned by one lane)
      const float* g1p = lngB + (l*2+1)*CC;
      const float* b1p = lnbB + (l*2+1)*CC;
      float2v cm2 = {cmP,cmP}, cr2 = {crP,crP};
      #pragma unroll
      for (int tile=0; tile<12; tile++){
        int co = tile*16 + quad*4;
        float4 xv = *(const float4*)&ping[row*XSF + co];
        float2v x01 = {xv.x, xv.y}, x23 = {xv.z, xv.w};
        float2v v01 = {acc[tile][0], acc[tile][1]};
        float2v v23 = {acc[tile][2], acc[tile][3]};
        float2v a01 = fma2((v01-cm2)*cr2, (float2v){g1p[co],   g1p[co+1]},
                           (float2v){b1p[co],   b1p[co+1]});
        float2v a23 = fma2((v23-cm2)*cr2, (float2v){g1p[co+2], g1p[co+3]},
                           (float2v){b1p[co+2], b1p[co+3]});
        float4 ov = make_float4(x01.x + geluf(a01.x), x01.y + geluf(a01.y),
                                x23.x + geluf(a23.x), x23.y + geluf(a23.y));
        *(float4*)&ping[row*XSF + co] = ov;
      }
    }
    __syncthreads();   // P6 writes visible before next layer's P1
  }

  if (outmode == 0){
    #pragma unroll
    for (int k=0;k<3;k++){
      int task = k*256 + tid;
      int r = task/24, cn = task%24, c0 = cn*8;
      float4 u0 = *(float4*)&ping[(16+r)*XSF + c0];
      float4 u1 = *(float4*)&ping[(16+r)*XSF + c0 + 4];
      int4 pk;
      pk.x = (int)packbf2(u0.x, u0.y); pk.y = (int)packbf2(u0.z, u0.w);
      pk.z = (int)packbf2(u1.x, u1.y); pk.w = (int)packbf2(u1.z, u1.w);
      *(int4*)(outb + ((size_t)b*TTT + t0 + r)*CC + c0) = pk;
    }
    return;
  }

  // ---- proj (29x192) on center rows: waves 1,2 own rows 16..47 ----
  if (w == 1 || w == 2){
    Frag bfp[6];
    #pragma unroll
    for (int k=0;k<6;k++){
      int kk = k*32 + quad*8;
      float4 u0 = *(float4*)&ping[row*XSF + kk];
      float4 u1 = *(float4*)&ping[row*XSF + kk + 4];
      bfp[k].i = make_int4((int)packbf2(u0.x,u0.y), (int)packbf2(u0.z,u0.w),
                           (int)packbf2(u1.x,u1.y), (int)packbf2(u1.z,u1.w));
    }
    floatx4 acc2[2];
    acc2[0] = (floatx4){0.f,0.f,0.f,0.f};
    acc2[1] = (floatx4){0.f,0.f,0.f,0.f};
    #pragma unroll
    for (int ct2=0; ct2<2; ct2++){
      #pragma unroll
      for (int k=0;k<6;k++){
        Frag af;
        af.i = *(const int4*)(projW + ((size_t)(ct2*6 + k)*64 + lane)*8);
        acc2[ct2] = __builtin_amdgcn_mfma_f32_16x16x32_bf16(af.s, bfp[k].s, acc2[ct2], 0,0,0);
      }
    }
    int rt = row - 16;                  // 0..31
    float mv = mrow[row];
    #pragma unroll
    for (int ct2=0; ct2<2; ct2++){
      int cobase = ct2*16 + quad*4;
      #pragma unroll
      for (int r=0;r<4;r++){
        int co = cobase + r;
        if (co < PP) pro[rt*30 + co] = (acc2[ct2][r] + projB[co]) * mv;
      }
    }
  }
  __syncthreads();
  // ---- RQS spline on 32 lanes ----
  if (tid < 32){
    const float scv = 0.07216878364870323f;   // 1/sqrt(192)
    int tg = t0 + tid;
    float m = mrow[16+tid];
    float* z0p = z + ((size_t)b*2 + zs)*TTT + tg;
    float* z1p = z + ((size_t)b*2 + (1-zs))*TTT + tg;
    float xs = *z1p;
    float uw[10], uh[10], ud[9];
    #pragma unroll
    for (int k=0;k<10;k++) uw[k]=pro[tid*30+k]*scv;
    #pragma unroll
    for (int k=0;k<10;k++) uh[k]=pro[tid*30+10+k]*scv;
    #pragma unroll
    for (int k=0;k<9;k++)  ud[k]=pro[tid*30+20+k];
    bool inside = (xs >= -5.f) && (xs <= 5.f);
    float xc = fminf(fmaxf(xs,-5.f),5.f);
    float mx=uw[0];
    #pragma unroll
    for (int k=1;k<10;k++) mx=fmaxf(mx,uw[k]);
    float sw=0.f; float wd[10];
    #pragma unroll
    for (int k=0;k<10;k++){ wd[k]=__expf(uw[k]-mx); sw+=wd[k]; }
    float invw = 1.f/sw;
    #pragma unroll
    for (int k=0;k<10;k++) wd[k]=fmaf(0.99f*invw, wd[k], 1e-3f);
    float mh=uh[0];
    #pragma unroll
    for (int k=1;k<10;k++) mh=fmaxf(mh,uh[k]);
    float sh=0.f; float ht[10];
    #pragma unroll
    for (int k=0;k<10;k++){ ht[k]=__expf(uh[k]-mh); sh+=ht[k]; }
    float invh = 1.f/sh;
    #pragma unroll
    for (int k=0;k<10;k++) ht[k]=fmaf(0.99f*invh, ht[k], 1e-3f);
    float cw=-5.f, icw=-5.f, iw=1.f; int idx=0;
    #pragma unroll
    for (int i2=0;i2<10;i2++){
      float nw = (i2==9) ? 5.f : fmaf(10.f, wd[i2], cw);
      if (cw <= xc){ idx=i2; icw=cw; iw=nw-cw; }
      cw=nw;
    }
    float ch=-5.f, ich=-5.f, ih=1.f;
    #pragma unroll
    for (int i2=0;i2<10;i2++){
      float nh = (i2==9) ? 5.f : fmaf(10.f, ht[i2], ch);
      if (i2==idx){ ich=ch; ih=nh-ch; }
      ch=nh;
    }
    const float UDC = logf(expm1f(0.999f));
    float d0=1.f, d1=1.f;
    #pragma unroll
    for (int k=0;k<11;k++){
      float uu = (k==0 || k==10) ? UDC : ud[k-1];
      float dk = 1e-3f + softplus_f(uu);
      if (k==idx)   d0=dk;
      if (k==idx+1) d1=dk;
    }
    float idel = ih/iw;
    float th = (xc-icw)/iw;
    float t1m = th*(1.f-th);
    float den = idel + (d0+d1-2.f*idel)*t1m;
    float outv = ich + ih*(idel*th*th + d0*t1m)/den;
    float omt = 1.f-th;
    float dnum = idel*idel*(d1*th*th + 2.f*idel*t1m + d0*omt*omt);
    float lad = logf(dnum) - 2.f*logf(den);
    float y = inside ? outv : xs;
    lad = inside ? lad : 0.f;
    *z1p = y*m;
    *z0p = (*z0p)*m;
    float lm = lad*m;
    lm += __shfl_xor(lm, 1); lm += __shfl_xor(lm, 2);
    lm += __shfl_xor(lm, 4); lm += __shfl_xor(lm, 8);
    lm += __shfl_xor(lm, 16);
    if (tid == 0) atomicAdd(acco + b, -lm);
  }
}

// ---------------- z init ----------------
__global__ __launch_bounds__(256) void init_z_k(
    const float* __restrict__ e_q, const float* __restrict__ mask,
    const float* __restrict__ pm, const float* __restrict__ pl,
    float* __restrict__ z, float* __restrict__ acc){
  __shared__ float red[256];
  int b = blockIdx.y; int t = blockIdx.x*256 + threadIdx.x;
  float m = mask[(size_t)b*TTT + t];
  float pl0=pl[0], pl1=pl[1];
  float e0 = e_q[((size_t)b*2+0)*TTT + t]*m;
  float e1 = e_q[((size_t)b*2+1)*TTT + t]*m;
  z[((size_t)b*2+0)*TTT + t] = fmaf(__expf(pl0), e0, pm[0])*m;
  z[((size_t)b*2+1)*TTT + t] = fmaf(__expf(pl1), e1, pm[1])*m;
  float contrib = -0.5f*(LOG2PI_F + e0*e0)*m - 0.5f*(LOG2PI_F + e1*e1)*m - (pl0+pl1)*m;
  int tid = threadIdx.x;
  red[tid] = contrib;
  __syncthreads();
  for (int o=128;o>0;o>>=1){ if (tid<o) red[tid]+=red[tid+o]; __syncthreads(); }
  if (tid==0) atomicAdd(acc+b, red[0]);
}

// ---------------- between p-flows and f-flows ----------------
__global__ __launch_bounds__(256) void final_pre_k(
    float* __restrict__ z, const float* __restrict__ w_in, const float* __restrict__ mask,
    const float* __restrict__ am, const float* __restrict__ al, float* __restrict__ acc){
  __shared__ float red[256];
  int b = blockIdx.y; int t = blockIdx.x*256 + threadIdx.x;
  float m = mask[(size_t)b*TTT + t];
  float zu  = z[((size_t)b*2+0)*TTT + t];
  float z1v = z[((size_t)b*2+1)*TTT + t];
  float wv  = w_in[(size_t)b*TTT + t];
  float u  = m / (1.f + __expf(-zu));
  float z0 = (wv - u)*m;
  float y0 = logf(fmaxf(z0, 1e-5f))*m;
  float al0=al[0], al1=al[1];
  z[((size_t)b*2+0)*TTT + t] = fmaf(__expf(al0), y0,  am[0])*m;
  z[((size_t)b*2+1)*TTT + t] = fmaf(__expf(al1), z1v, am[1])*m;
  float contrib = -(logsig_f(zu)+logsig_f(-zu))*m + y0 - (al0+al1)*m;
  int tid = threadIdx.x;
  red[tid] = contrib;
  __syncthreads();
  for (int o=128;o>0;o>>=1){ if (tid<o) red[tid]+=red[tid+o]; __syncthreads(); }
  if (tid==0) atomicAdd(acc+b, red[0]);
}

// ---------------- final 0.5(log2pi + z^2) sum ----------------
__global__ __launch_bounds__(256) void final_post_k(
    const float* __restrict__ z, const float* __restrict__ mask, float* __restrict__ acc){
  __shared__ float red[256];
  int b = blockIdx.y; int t = blockIdx.x*256 + threadIdx.x;
  float m = mask[(size_t)b*TTT + t];
  float z0 = z[((size_t)b*2+0)*TTT + t];
  float z1 = z[((size_t)b*2+1)*TTT + t];
  float contrib = 0.5f*(LOG2PI_F + z0*z0)*m + 0.5f*(LOG2PI_F + z1*z1)*m;
  int tid = threadIdx.x;
  red[tid] = contrib;
  __syncthreads();
  for (int o=128;o>0;o>>=1){ if (tid<o) red[tid]+=red[tid+o]; __syncthreads(); }
  if (tid==0) atomicAdd(acc+b, red[0]);
}

__global__ void write_out_k(const float* __restrict__ acc, float* __restrict__ out, int n){
  int i = threadIdx.x;
  if (i < n) out[i] = acc[i];
}

extern "C" void kernel_launch(void* const* d_in, const int* in_sizes, int n_in,
                              void* d_out, int out_size, void* d_ws, size_t ws_size,
                              hipStream_t stream){
  (void)n_in; (void)out_size; (void)ws_size;
  const float* x         = (const float*)d_in[0];
  const float* mask      = (const float*)d_in[1];
  const float* w_in      = (const float*)d_in[2];
  const float* e_q       = (const float*)d_in[3];
  const float* pre_w     = (const float*)d_in[4];
  const float* pre_b     = (const float*)d_in[5];
  const float* proj_w    = (const float*)d_in[6];
  const float* proj_b    = (const float*)d_in[7];
  const float* dds_dep_w = (const float*)d_in[8];
  const float* dds_dep_b = (const float*)d_in[9];
  const float* dds_pw_w  = (const float*)d_in[10];
  const float* dds_pw_b  = (const float*)d_in[11];
  const float* dds_ln_g  = (const float*)d_in[12];
  const float* dds_ln_b  = (const float*)d_in[13];
  const float* post_pre_w  = (const float*)d_in[14];
  const float* post_pre_b  = (const float*)d_in[15];
  const float* post_proj_w = (const float*)d_in[16];
  const float* post_proj_b = (const float*)d_in[17];
  const float* pdds_dep_w  = (const float*)d_in[18];
  const float* pdds_dep_b  = (const float*)d_in[19];
  const float* pdds_pw_w   = (const float*)d_in[20];
  const float* pdds_pw_b   = (const float*)d_in[21];
  const float* pdds_ln_g   = (const float*)d_in[22];
  const float* pdds_ln_b   = (const float*)d_in[23];
  const float* aff_m    = (const float*)d_in[24];
  const float* aff_logs = (const float*)d_in[25];
  const float* f_pre_w  = (const float*)d_in[26];
  const float* f_pre_b  = (const float*)d_in[27];
  const float* f_dep_w  = (const float*)d_in[28];
  const float* f_dep_b  = (const float*)d_in[29];
  const float* f_pw_w   = (const float*)d_in[30];
  const float* f_pw_b   = (const float*)d_in[31];
  const float* f_ln_g   = (const float*)d_in[32];
  const float* f_ln_b   = (const float*)d_in[33];
  const float* f_proj_w = (const float*)d_in[34];
  const float* f_proj_b = (const float*)d_in[35];
  const float* paff_m    = (const float*)d_in[36];
  const float* paff_logs = (const float*)d_in[37];
  const float* p_pre_w  = (const float*)d_in[38];
  const float* p_pre_b  = (const float*)d_in[39];
  const float* p_dep_w  = (const float*)d_in[40];
  const float* p_dep_b  = (const float*)d_in[41];
  const float* p_pw_w   = (const float*)d_in[42];
  const float* p_pw_b   = (const float*)d_in[43];
  const float* p_ln_g   = (const float*)d_in[44];
  const float* p_ln_b   = (const float*)d_in[45];
  const float* p_proj_w = (const float*)d_in[46];
  const float* p_proj_b = (const float*)d_in[47];

  int Bn = in_sizes[0] / (CC*TTT);
  size_t big2 = (size_t)Bn*CC*TTT;
  unsigned short* xT = (unsigned short*)d_ws;
  unsigned short* A  = xT + big2;
  unsigned short* Bb = A  + big2;
  unsigned short* H  = Bb + big2;
  unsigned short* GP = H  + big2;
  unsigned short* Wb = GP + big2;
  size_t wtot = 33*(size_t)WSLOT + 8*(size_t)PSW;
  float* zbuf = (float*)(Wb + ((wtot + 7) & ~(size_t)7));
  float* acc  = zbuf + (size_t)Bn*2*TTT;

  hipMemsetAsync(acc, 0, Bn*sizeof(float), stream);
  convert_w_k<<<(int)((wtot + 255)/256), 256, 0, stream>>>(
      pre_w, proj_w, post_proj_w, dds_pw_w, pdds_pw_w, p_pw_w, f_pw_w,
      p_proj_w, f_proj_w, Wb);

  dim3 g32(TTT/32, Bn), g256(TTT/256, Bn);
  dim3 b256(256);

  unsigned short* W_pre      = Wb + 0*(size_t)WSLOT;
  unsigned short* W_proj     = Wb + 1*(size_t)WSLOT;
  unsigned short* W_postproj = Wb + 2*(size_t)WSLOT;
  unsigned short* W_dds      = Wb + 3*(size_t)WSLOT;
  unsigned short* W_pdds     = Wb + 6*(size_t)WSLOT;
  unsigned short* W_ppw      = Wb + 9*(size_t)WSLOT;
  unsigned short* W_fpw      = Wb + 21*(size_t)WSLOT;
  unsigned short* W_pproj    = Wb + 33*(size_t)WSLOT;
  unsigned short* W_fproj    = W_pproj + 4*(size_t)PSW;

  transpose_x_k<<<g32, b256, 0, stream>>>(x, xT);

  // ---- h path ----
  conv_cc_k<<<g32, b256, 0, stream>>>(xT, W_pre, pre_b, mask, nullptr, A, 0);
  mega_dds_k<<<g32, b256, 0, stream>>>(A, nullptr, 0, nullptr, Bb, mask,
      dds_dep_w, dds_dep_b, dds_ln_g, dds_ln_b, dds_pw_b, nullptr, nullptr,
      W_dds, 0, 0, nullptr, nullptr, nullptr, 0, acc);
  conv_cc_k<<<g32, b256, 0, stream>>>(Bb, W_proj, proj_b, mask, nullptr, H, 1);

  // ---- hw path ----
  mega_dds_k<<<g32, b256, 0, stream>>>(nullptr, w_in, TTT, nullptr, A, mask,
      pdds_dep_w, pdds_dep_b, pdds_ln_g, pdds_ln_b, pdds_pw_b, post_pre_w, post_pre_b,
      W_pdds, 1, 0, nullptr, nullptr, nullptr, 0, acc);
  conv_cc_k<<<g32, b256, 0, stream>>>(A, W_postproj, post_proj_b, mask, H, GP, 2);

  // ---- init z ----
  init_z_k<<<g256, b256, 0, stream>>>(e_q, mask, paff_m, paff_logs, zbuf, acc);

  // ---- 4 posterior flows (g = GP) ----
  for (int f=0; f<4; f++){
    int s = f & 1;
    mega_dds_k<<<g32, b256, 0, stream>>>(nullptr, zbuf + (size_t)s*TTT, 2*TTT, GP, nullptr, mask,
        p_dep_w + (size_t)f*3*CC*3, p_dep_b + (size_t)f*3*CC,
        p_ln_g + (size_t)f*3*2*CC, p_ln_b + (size_t)f*3*2*CC,
        p_pw_b + (size_t)f*3*CC,
        p_pre_w + (size_t)f*CC, p_pre_b + (size_t)f*CC,
        W_ppw + (size_t)f*3*WSLOT, 1, 1,
        W_pproj + (size_t)f*PSW, p_proj_b + (size_t)f*PP, zbuf, s, acc);
  }

  // ---- transition ----
  final_pre_k<<<g256, b256, 0, stream>>>(zbuf, w_in, mask, aff_m, aff_logs, acc);

  // ---- 4 flows (g = H) ----
  for (int f=0; f<4; f++){
    int s = f & 1;
    mega_dds_k<<<g32, b256, 0, stream>>>(nullptr, zbuf + (size_t)s*TTT, 2*TTT, H, nullptr, mask,
        f_dep_w + (size_t)f*3*CC*3, f_dep_b + (size_t)f*3*CC,
        f_ln_g + (size_t)f*3*2*CC, f_ln_b + (size_t)f*3*2*CC,
        f_pw_b + (size_t)f*3*CC,
        f_pre_w + (size_t)f*CC, f_pre_b + (size_t)f*CC,
        W_fpw + (size_t)f*3*WSLOT, 1, 1,
        W_fproj + (size_t)f*PSW, f_proj_b + (size_t)f*PP, zbuf, s, acc);
  }

  final_post_k<<<g256, b256, 0, stream>>>(zbuf, mask, acc);
  write_out_k<<<1, 64, 0, stream>>>(acc, (float*)d_out, Bn);
}

// Round 9
// 776.512 us; speedup vs baseline: 1.5090x; 1.5090x over previous
//
#include <hip/hip_runtime.h>
#include <math.h>

#define CC 192
#define TTT 768
#define PP 29
#define LOG2PI_F 1.8378770664093453f
#define WSLOT 36864   // swizzled 192x192 slot (elements)
#define PSW 6144      // swizzled 32x192 proj slot (elements)
#define XS 200        // ushort stride for conv_cc/transpose LDS tiles
#define XS2 196       // ushort stride for mega ping (392B rows -> 2-bank/row shift, free)
#define PARL 1728     // 9*192 floats per layer param block

typedef __attribute__((ext_vector_type(8))) short short8;
typedef __attribute__((ext_vector_type(4))) float floatx4;
typedef __attribute__((ext_vector_type(2))) float float2v;
union Frag { int4 i; short8 s; };

__device__ __forceinline__ float2v fma2(float2v a, float2v b, float2v c){
  return __builtin_elementwise_fma(a, b, c);
}
__device__ __forceinline__ float geluf(float x){
  float u = 1.5957691216057308f * (x + 0.044715f*x*x*x);
  return x * __builtin_amdgcn_rcpf(1.f + __expf(-u));
}
__device__ __forceinline__ float softplus_f(float x){
  return (x > 20.f) ? x : log1pf(__expf(x));
}
__device__ __forceinline__ float logsig_f(float x){
  return -softplus_f(-x);
}
__device__ __forceinline__ unsigned short f2bf(float f){
  unsigned int u = __builtin_bit_cast(unsigned int, f);
  u += 0x7fffu + ((u >> 16) & 1u);
  return (unsigned short)(u >> 16);
}
__device__ __forceinline__ unsigned int packbf2(float a0, float a1){
  return (unsigned int)f2bf(a0) | ((unsigned int)f2bf(a1) << 16);
}
__device__ __forceinline__ void unbf2(unsigned int u, float& lo, float& hi){
  lo = __builtin_bit_cast(float, u << 16);
  hi = __builtin_bit_cast(float, u & 0xffff0000u);
}
__device__ __forceinline__ float2v unbf2v(unsigned int u){
  float2v r;
  r.x = __builtin_bit_cast(float, u << 16);
  r.y = __builtin_bit_cast(float, u & 0xffff0000u);
  return r;
}
__device__ __forceinline__ void unp8(int4 v, float* o){
  unsigned int* p = (unsigned int*)&v;
  unbf2(p[0], o[0], o[1]); unbf2(p[1], o[2], o[3]);
  unbf2(p[2], o[4], o[5]); unbf2(p[3], o[6], o[7]);
}
__device__ __forceinline__ void f4arr(float4 v, float* o){ o[0]=v.x;o[1]=v.y;o[2]=v.z;o[3]=v.w; }
__device__ __forceinline__ float2v pick2(float4 a, float4 b, int p){
  // element pair 2p,2p+1 of the 8-vector (a.xyzw, b.xyzw)
  switch(p){
    case 0: return (float2v){a.x, a.y};
    case 1: return (float2v){a.z, a.w};
    case 2: return (float2v){b.x, b.y};
    default: return (float2v){b.z, b.w};
  }
}

// ---------------- weight f32 -> bf16 swizzled fragment order ----------------
__global__ __launch_bounds__(256) void convert_w_k(
    const float* __restrict__ p0, const float* __restrict__ p1,
    const float* __restrict__ p2, const float* __restrict__ p3,
    const float* __restrict__ p4, const float* __restrict__ p5,
    const float* __restrict__ p6, const float* __restrict__ p7,
    const float* __restrict__ p8, unsigned short* __restrict__ Wb){
  int i = blockIdx.x*256 + threadIdx.x;
  const int totalA = 33*WSLOT;
  const int total = totalA + 8*PSW;
  if (i >= total) return;
  if (i < totalA){
    int slot = i / WSLOT, j = i % WSLOT;
    int e = j & 7, lane = (j>>3) & 63, kt = j >> 9;
    int k = kt % 6, tile = kt / 6;
    int co = tile*16 + (lane & 15);
    int kk = k*32 + (lane>>4)*8 + e;
    int r = co*CC + kk;
    const float* src;
    if      (slot == 0) src = p0 + r;
    else if (slot == 1) src = p1 + r;
    else if (slot == 2) src = p2 + r;
    else if (slot < 6)  src = p3 + (size_t)(slot-3)*WSLOT + r;
    else if (slot < 9)  src = p4 + (size_t)(slot-6)*WSLOT + r;
    else if (slot < 21) src = p5 + (size_t)(slot-9)*WSLOT + r;
    else                src = p6 + (size_t)(slot-21)*WSLOT + r;
    Wb[i] = f2bf(*src);
  } else {
    int r2 = i - totalA;
    int ps = r2 / PSW, j = r2 % PSW;
    int e = j & 7, lane = (j>>3) & 63, kt = j >> 9;
    int k = kt % 6, tile = kt / 6;
    int co = tile*16 + (lane & 15); if (co > PP-1) co = PP-1;
    int kk = k*32 + (lane>>4)*8 + e;
    const float* base = (ps < 4) ? (p7 + (size_t)ps*PP*CC) : (p8 + (size_t)(ps-4)*PP*CC);
    Wb[i] = f2bf(base[co*CC + kk]);
  }
}

// ---------------- per-layer params -> [set][layer][9][192] f32 ----------------
// arrays: 0..2 dw taps, 3 db, 4 g0, 5 b0, 6 g1, 7 b1, 8 pb
__global__ __launch_bounds__(256) void pack_par_k(
    const float* __restrict__ dds_dep_w, const float* __restrict__ dds_dep_b,
    const float* __restrict__ dds_ln_g,  const float* __restrict__ dds_ln_b,
    const float* __restrict__ dds_pw_b,
    const float* __restrict__ pdds_dep_w, const float* __restrict__ pdds_dep_b,
    const float* __restrict__ pdds_ln_g,  const float* __restrict__ pdds_ln_b,
    const float* __restrict__ pdds_pw_b,
    const float* __restrict__ p_dep_w, const float* __restrict__ p_dep_b,
    const float* __restrict__ p_ln_g,  const float* __restrict__ p_ln_b,
    const float* __restrict__ p_pw_b,
    const float* __restrict__ f_dep_w, const float* __restrict__ f_dep_b,
    const float* __restrict__ f_ln_g,  const float* __restrict__ f_ln_b,
    const float* __restrict__ f_pw_b,
    float* __restrict__ P){
  int i = blockIdx.x*256 + threadIdx.x;
  const int total = 30*PARL;
  if (i >= total) return;
  int ls = i / PARL, r = i % PARL;
  int arr = r / 192, c = r % 192;
  const float *dep_w, *dep_b, *ln_g, *ln_b, *pw_b;
  int l;
  if (ls < 3){
    l = ls; dep_w = dds_dep_w; dep_b = dds_dep_b; ln_g = dds_ln_g; ln_b = dds_ln_b; pw_b = dds_pw_b;
  } else if (ls < 6){
    l = ls-3; dep_w = pdds_dep_w; dep_b = pdds_dep_b; ln_g = pdds_ln_g; ln_b = pdds_ln_b; pw_b = pdds_pw_b;
  } else if (ls < 18){
    int f = (ls-6)/3; l = (ls-6)%3;
    dep_w = p_dep_w + (size_t)f*3*CC*3; dep_b = p_dep_b + (size_t)f*3*CC;
    ln_g = p_ln_g + (size_t)f*3*2*CC;  ln_b = p_ln_b + (size_t)f*3*2*CC;
    pw_b = p_pw_b + (size_t)f*3*CC;
  } else {
    int f = (ls-18)/3; l = (ls-18)%3;
    dep_w = f_dep_w + (size_t)f*3*CC*3; dep_b = f_dep_b + (size_t)f*3*CC;
    ln_g = f_ln_g + (size_t)f*3*2*CC;  ln_b = f_ln_b + (size_t)f*3*2*CC;
    pw_b = f_pw_b + (size_t)f*3*CC;
  }
  float v;
  if      (arr < 3)  v = dep_w[((size_t)l*CC + c)*3 + arr];
  else if (arr == 3) v = dep_b[(size_t)l*CC + c];
  else if (arr == 4) v = ln_g[((size_t)l*2+0)*CC + c];
  else if (arr == 5) v = ln_b[((size_t)l*2+0)*CC + c];
  else if (arr == 6) v = ln_g[((size_t)l*2+1)*CC + c];
  else if (arr == 7) v = ln_b[((size_t)l*2+1)*CC + c];
  else               v = pw_b[(size_t)l*CC + c];
  P[i] = v;
}

// ---------------- x f32 [B][C][T] -> bf16 [B][T][C] ----------------
__global__ __launch_bounds__(256) void transpose_x_k(
    const float* __restrict__ x, unsigned short* __restrict__ xT){
  __shared__ unsigned short tile[32*XS];
  int b = blockIdx.y, t0 = blockIdx.x*32, tid = threadIdx.x;
  int tl4 = (tid & 7)*4, cr = tid >> 3;
  #pragma unroll
  for (int rnd=0; rnd<6; rnd++){
    int c = rnd*32 + cr;
    float4 v4 = *(const float4*)(x + ((size_t)b*CC + c)*TTT + t0 + tl4);
    tile[(tl4+0)*XS + c] = f2bf(v4.x);
    tile[(tl4+1)*XS + c] = f2bf(v4.y);
    tile[(tl4+2)*XS + c] = f2bf(v4.z);
    tile[(tl4+3)*XS + c] = f2bf(v4.w);
  }
  __syncthreads();
  #pragma unroll
  for (int k=0;k<3;k++){
    int task = k*256 + tid;
    int row = task/24, cn = task%24;
    *(int4*)(xT + ((size_t)b*TTT + t0 + row)*CC + cn*8) = *(const int4*)&tile[row*XS + cn*8];
  }
}

// ---------------- conv 192x192 bf16 MFMA, t-major bf16 in/out ----------------
__global__ __launch_bounds__(256) void conv_cc_k(
    const unsigned short* __restrict__ in, const unsigned short* __restrict__ Wsw,
    const float* __restrict__ bias, const float* __restrict__ mask,
    const unsigned short* __restrict__ addsrc, unsigned short* __restrict__ outb, int mode){
  __shared__ unsigned short bufX[32*XS];
  __shared__ unsigned short bufY[32*XS];
  __shared__ float marr[32];
  int b = blockIdx.y, t0 = blockIdx.x*32, tid = threadIdx.x;
  #pragma unroll
  for (int k=0;k<3;k++){
    int task = k*256 + tid;
    int row = task/24, cn = task%24;
    const unsigned short* src = in + ((size_t)b*TTT + t0 + row)*CC + cn*8;
    *(int4*)&bufX[row*XS + cn*8] = *(const int4*)src;
    if (mode == 2){
      const unsigned short* s2 = addsrc + ((size_t)b*TTT + t0 + row)*CC + cn*8;
      *(int4*)&bufY[row*XS + cn*8] = *(const int4*)s2;
    }
  }
  if (tid >= 128 && tid < 160) marr[tid-128] = mask[(size_t)b*TTT + t0 + (tid-128)];
  __syncthreads();
  int w = tid >> 6, lane = tid & 63;
  int n16 = lane & 15, quad = lane >> 4;
  Frag af[3][6];
  #pragma unroll
  for (int ct=0; ct<3; ct++){
    int tile = w*3 + ct;
    #pragma unroll
    for (int k=0;k<6;k++)
      af[ct][k].i = *(const int4*)(Wsw + ((size_t)(tile*6 + k)*64 + lane)*8);
  }
  floatx4 acc[3][2];
  #pragma unroll
  for (int ct=0;ct<3;ct++)
    #pragma unroll
    for (int tt=0;tt<2;tt++)
      acc[ct][tt] = (floatx4){0.f,0.f,0.f,0.f};
  #pragma unroll
  for (int k=0;k<6;k++){
    Frag bf[2];
    #pragma unroll
    for (int tt=0;tt<2;tt++)
      bf[tt].i = *(const int4*)&bufX[(tt*16+n16)*XS + k*32 + quad*8];
    #pragma unroll
    for (int ct=0;ct<3;ct++)
      #pragma unroll
      for (int tt=0;tt<2;tt++)
        acc[ct][tt] = __builtin_amdgcn_mfma_f32_16x16x32_bf16(af[ct][k].s, bf[tt].s, acc[ct][tt], 0,0,0);
  }
  __syncthreads();
  #pragma unroll
  for (int ct=0;ct<3;ct++){
    int cobase = w*48 + ct*16 + quad*4;
    float4 b4 = *(const float4*)(bias + cobase);
    float ba[4] = {b4.x, b4.y, b4.z, b4.w};
    #pragma unroll
    for (int tt=0;tt<2;tt++){
      int t = tt*16 + n16;
      float mv = (mode >= 1) ? marr[t] : 1.f;
      float av[4] = {0.f,0.f,0.f,0.f};
      if (mode == 2){
        uint2 uy = *(uint2*)&bufY[t*XS + cobase];
        unbf2(uy.x, av[0], av[1]); unbf2(uy.y, av[2], av[3]);
      }
      float hh[4];
      #pragma unroll
      for (int r=0;r<4;r++){
        float v = acc[ct][tt][r] + ba[r];
        if (mode >= 1) v *= mv;
        if (mode == 2) v += av[r];
        hh[r] = v;
      }
      uint2 wv; wv.x = packbf2(hh[0], hh[1]); wv.y = packbf2(hh[2], hh[3]);
      *(uint2*)&bufX[t*XS + cobase] = wv;
    }
  }
  __syncthreads();
  #pragma unroll
  for (int k=0;k<3;k++){
    int task = k*256 + tid;
    int row = task/24, cn = task%24;
    *(int4*)(outb + ((size_t)b*TTT + t0 + row)*CC + cn*8) = *(const int4*)&bufX[row*XS + cn*8];
  }
}

// ---------------- mega DDS v4: bf16 ping + LDS param staging (double-buffered) ----------------
__global__ __launch_bounds__(256,3) void mega_dds_k(
    const unsigned short* __restrict__ in,
    const float* __restrict__ zsrc, int zstride,
    const unsigned short* __restrict__ g,
    unsigned short* __restrict__ outb,
    const float* __restrict__ mask,
    const float* __restrict__ parP,     // 3 layers x PARL floats
    const float* __restrict__ pw1, const float* __restrict__ pb1,
    const unsigned short* __restrict__ Wsw,
    int srcmode, int outmode,
    const unsigned short* __restrict__ projW, const float* __restrict__ projB,
    float* __restrict__ z, int zs, float* __restrict__ acco){
  __shared__ unsigned short ping[64*XS2];   // bf16 [window row][c], in-place residual stream
  __shared__ float par[2][PARL];            // per-layer params, double-buffered
  __shared__ float mrow[64];
  float* pro = par[0];                      // alias: used only after all layers done

  int b = blockIdx.y, t0 = blockIdx.x*32, tid = threadIdx.x;
  int ws0 = t0 - 16;
  int w = tid >> 6, lane = tid & 63;
  int n16 = lane & 15, quad = lane >> 4;
  int row = w*16 + n16;                      // this lane's window row
  const float* mkb = mask + (size_t)b*TTT;
  const int dils[3] = {1,3,9};

  if (tid < 64){
    int gt = ws0 + tid;
    bool inr = (gt >= 0) && (gt < TTT);
    int gc = gt < 0 ? 0 : (gt > TTT-1 ? TTT-1 : gt);
    mrow[tid] = inr ? mkb[gc] : 0.f;
  }
  // stage layer-0 params
  #pragma unroll
  for (int k=0;k<7;k++){
    int i2 = k*256 + tid;
    if (i2 < PARL) par[0][i2] = parP[i2];
  }
  // ---- staging (pre-masked) ----
  if (srcmode == 0){
    #pragma unroll
    for (int k=0;k<6;k++){
      int task = k*256 + tid;
      int r = task/24, cn = task%24, c0 = cn*8;
      int gt = ws0 + r;
      bool inr = (gt >= 0) && (gt < TTT);
      int gc = gt < 0 ? 0 : (gt > TTT-1 ? TTT-1 : gt);
      float mv = inr ? mkb[gc] : 0.f;
      float hv[8];
      unp8(*(const int4*)(in + ((size_t)b*TTT + gc)*CC + c0), hv);
      uint2 w0, w1;
      w0.x = packbf2(hv[0]*mv, hv[1]*mv); w0.y = packbf2(hv[2]*mv, hv[3]*mv);
      w1.x = packbf2(hv[4]*mv, hv[5]*mv); w1.y = packbf2(hv[6]*mv, hv[7]*mv);
      *(uint2*)&ping[r*XS2 + c0]     = w0;
      *(uint2*)&ping[r*XS2 + c0 + 4] = w1;
    }
  } else {
    #pragma unroll
    for (int k=0;k<6;k++){
      int task = k*256 + tid;
      int r = task/24, cn = task%24, c0 = cn*8;
      int gt = ws0 + r;
      bool inr = (gt >= 0) && (gt < TTT);
      int gc = gt < 0 ? 0 : (gt > TTT-1 ? TTT-1 : gt);
      float mv = inr ? mkb[gc] : 0.f;
      float zv = inr ? zsrc[(size_t)b*zstride + gc] : 0.f;
      float hv[8];
      if (g){
        unp8(*(const int4*)(g + ((size_t)b*TTT + gc)*CC + c0), hv);
      } else {
        #pragma unroll
        for (int e=0;e<8;e++) hv[e] = 0.f;
      }
      float4 pwa = *(const float4*)(pw1 + c0);
      float4 pwb2 = *(const float4*)(pw1 + c0 + 4);
      float4 pba = *(const float4*)(pb1 + c0);
      float4 pbb2 = *(const float4*)(pb1 + c0 + 4);
      float pwv[8], pbv[8];
      f4arr(pwa, pwv); f4arr(pwb2, pwv+4);
      f4arr(pba, pbv); f4arr(pbb2, pbv+4);
      float ov[8];
      #pragma unroll
      for (int e=0;e<8;e++) ov[e] = (hv[e] + fmaf(pwv[e], zv, pbv[e]))*mv;
      uint2 w0, w1;
      w0.x = packbf2(ov[0], ov[1]); w0.y = packbf2(ov[2], ov[3]);
      w1.x = packbf2(ov[4], ov[5]); w1.y = packbf2(ov[6], ov[7]);
      *(uint2*)&ping[r*XS2 + c0]     = w0;
      *(uint2*)&ping[r*XS2 + c0 + 4] = w1;
    }
  }
  __syncthreads();

  // ---- 3 fused layers ----
  #pragma unroll
  for (int l=0; l<3; l++){
    const int dil = dils[l];
    const bool active = (l < 2) || (w == 1) || (w == 2);
    const float* pl = par[l & 1];
    Frag bfr[6];
    floatx4 acc[12];
    if (active){
      int iL = row - dil; iL = iL < 0 ? 0 : iL;
      int iR = row + dil; iR = iR > 63 ? 63 : iR;
      float ml = (row - dil >= 0) ? mrow[iL] : 0.f;
      float mc = mrow[row];
      float mr = (row + dil <= 63) ? mrow[iR] : 0.f;
      float2v ml2 = {ml,ml}, mc2 = {mc,mc}, mr2 = {mr,mr};
      float2v vv[24];
      float s = 0.f, q = 0.f;
      #pragma unroll
      for (int j=0;j<6;j++){
        int kk = j*32 + quad*8;
        uint2 a0 = *(uint2*)&ping[iL*XS2 + kk], a1 = *(uint2*)&ping[iL*XS2 + kk + 4];
        uint2 b0 = *(uint2*)&ping[row*XS2 + kk], b1 = *(uint2*)&ping[row*XS2 + kk + 4];
        uint2 c0v = *(uint2*)&ping[iR*XS2 + kk], c1 = *(uint2*)&ping[iR*XS2 + kk + 4];
        float2v XL[4] = {unbf2v(a0.x), unbf2v(a0.y), unbf2v(a1.x), unbf2v(a1.y)};
        float2v XC[4] = {unbf2v(b0.x), unbf2v(b0.y), unbf2v(b1.x), unbf2v(b1.y)};
        float2v XR[4] = {unbf2v(c0v.x), unbf2v(c0v.y), unbf2v(c1.x), unbf2v(c1.y)};
        // params: c-major LDS, quad-uniform -> broadcast b128 reads
        float4 w0a = *(const float4*)&pl[kk],       w0b = *(const float4*)&pl[kk+4];
        float4 w1a = *(const float4*)&pl[192+kk],   w1b = *(const float4*)&pl[192+kk+4];
        float4 w2a = *(const float4*)&pl[384+kk],   w2b = *(const float4*)&pl[384+kk+4];
        float4 dba = *(const float4*)&pl[576+kk],   dbb = *(const float4*)&pl[576+kk+4];
        #pragma unroll
        for (int p=0;p<4;p++){
          float2v val = fma2(pick2(w0a,w0b,p), XL[p]*ml2,
                        fma2(pick2(w1a,w1b,p), XC[p]*mc2,
                        fma2(pick2(w2a,w2b,p), XR[p]*mr2, pick2(dba,dbb,p))));
          vv[j*4+p] = val;
          s += val.x + val.y;
          q = fmaf(val.x, val.x, fmaf(val.y, val.y, q));
        }
      }
      s += __shfl_xor(s, 16); s += __shfl_xor(s, 32);
      q += __shfl_xor(q, 16); q += __shfl_xor(q, 32);
      float mm = s*(1.f/CC);
      float rr = rsqrtf(q*(1.f/CC) - mm*mm + 1e-5f);
      // P3: LN + gelu -> B fragments in registers
      {
        float2v mm2 = {mm,mm}, rr2 = {rr,rr};
        #pragma unroll
        for (int j=0;j<6;j++){
          int kk = j*32 + quad*8;
          float4 g0a = *(const float4*)&pl[768+kk], g0b = *(const float4*)&pl[768+kk+4];
          float4 b0a = *(const float4*)&pl[960+kk], b0b = *(const float4*)&pl[960+kk+4];
          unsigned int wwp[4];
          #pragma unroll
          for (int p=0;p<4;p++){
            float2v a = fma2((vv[j*4+p]-mm2)*rr2, pick2(g0a,g0b,p), pick2(b0a,b0b,p));
            wwp[p] = packbf2(geluf(a.x), geluf(a.y));
          }
          bfr[j].i = make_int4((int)wwp[0], (int)wwp[1], (int)wwp[2], (int)wwp[3]);
        }
      }
    }
    __syncthreads();   // all P1 ping reads done before in-place P6 writes
    // stage next layer's params (overlaps P4; visible at end-of-layer barrier)
    if (l < 2){
      const float* src = parP + (size_t)(l+1)*PARL;
      #pragma unroll
      for (int k=0;k<7;k++){
        int i2 = k*256 + tid;
        if (i2 < PARL) par[(l+1)&1][i2] = src[i2];
      }
    }
    if (active){
      // P4: stream all 12 A-tiles, B from registers
      const unsigned short* WL = Wsw + (size_t)l*WSLOT;
      #pragma unroll
      for (int tile=0; tile<12; tile++){
        acc[tile] = (floatx4){0.f,0.f,0.f,0.f};
        Frag af[6];
        #pragma unroll
        for (int k=0;k<6;k++)
          af[k].i = *(const int4*)(WL + ((size_t)(tile*6 + k)*64 + lane)*8);
        #pragma unroll
        for (int k=0;k<6;k++)
          acc[tile] = __builtin_amdgcn_mfma_f32_16x16x32_bf16(af[k].s, bfr[k].s, acc[tile], 0,0,0);
      }
      // bias + conv-LN stats (in-wave)
      float s2 = 0.f, q2 = 0.f;
      #pragma unroll
      for (int tile=0; tile<12; tile++){
        int co = tile*16 + quad*4;
        float4 pbv = *(const float4*)&pl[1536+co];
        float pba[4]; f4arr(pbv, pba);
        #pragma unroll
        for (int r=0;r<4;r++){
          acc[tile][r] += pba[r];
          float x = acc[tile][r];
          s2 += x; q2 = fmaf(x, x, q2);
        }
      }
      s2 += __shfl_xor(s2, 16); s2 += __shfl_xor(s2, 32);
      q2 += __shfl_xor(q2, 16); q2 += __shfl_xor(q2, 32);
      float cmP = s2*(1.f/CC);
      float crP = rsqrtf(q2*(1.f/CC) - cmP*cmP + 1e-5f);
      // P6: LN + gelu + residual, in-place (each 8B owned by one lane)
      float2v cm2 = {cmP,cmP}, cr2 = {crP,crP};
      #pragma unroll
      for (int tile=0; tile<12; tile++){
        int co = tile*16 + quad*4;
        float4 g1v = *(const float4*)&pl[1152+co];
        float4 b1v = *(const float4*)&pl[1344+co];
        uint2 ux = *(uint2*)&ping[row*XS2 + co];
        float2v x01 = unbf2v(ux.x), x23 = unbf2v(ux.y);
        float2v v01 = {acc[tile][0], acc[tile][1]};
        float2v v23 = {acc[tile][2], acc[tile][3]};
        float2v a01 = fma2((v01-cm2)*cr2, (float2v){g1v.x,g1v.y}, (float2v){b1v.x,b1v.y});
        float2v a23 = fma2((v23-cm2)*cr2, (float2v){g1v.z,g1v.w}, (float2v){b1v.z,b1v.w});
        uint2 wv;
        wv.x = packbf2(x01.x + geluf(a01.x), x01.y + geluf(a01.y));
        wv.y = packbf2(x23.x + geluf(a23.x), x23.y + geluf(a23.y));
        *(uint2*)&ping[row*XS2 + co] = wv;
      }
    }
    __syncthreads();   // P6 writes + par staging visible
  }

  if (outmode == 0){
    #pragma unroll
    for (int k=0;k<3;k++){
      int task = k*256 + tid;
      int r = task/24, cn = task%24, c0 = cn*8;
      uint2 u0 = *(uint2*)&ping[(16+r)*XS2 + c0];
      uint2 u1 = *(uint2*)&ping[(16+r)*XS2 + c0 + 4];
      *(int4*)(outb + ((size_t)b*TTT + t0 + r)*CC + c0) =
          make_int4((int)u0.x, (int)u0.y, (int)u1.x, (int)u1.y);
    }
    return;
  }

  // ---- proj (29x192) on center rows: waves 1,2 own rows 16..47 ----
  if (w == 1 || w == 2){
    Frag bfp[6];
    #pragma unroll
    for (int k=0;k<6;k++){
      int kk = k*32 + quad*8;
      uint2 u0 = *(uint2*)&ping[row*XS2 + kk];
      uint2 u1 = *(uint2*)&ping[row*XS2 + kk + 4];
      bfp[k].i = make_int4((int)u0.x, (int)u0.y, (int)u1.x, (int)u1.y);
    }
    floatx4 acc2[2];
    acc2[0] = (floatx4){0.f,0.f,0.f,0.f};
    acc2[1] = (floatx4){0.f,0.f,0.f,0.f};
    #pragma unroll
    for (int ct2=0; ct2<2; ct2++){
      #pragma unroll
      for (int k=0;k<6;k++){
        Frag af;
        af.i = *(const int4*)(projW + ((size_t)(ct2*6 + k)*64 + lane)*8);
        acc2[ct2] = __builtin_amdgcn_mfma_f32_16x16x32_bf16(af.s, bfp[k].s, acc2[ct2], 0,0,0);
      }
    }
    int rt = row - 16;                  // 0..31
    float mv = mrow[row];
    #pragma unroll
    for (int ct2=0; ct2<2; ct2++){
      int cobase = ct2*16 + quad*4;
      #pragma unroll
      for (int r=0;r<4;r++){
        int co = cobase + r;
        if (co < PP) pro[rt*30 + co] = (acc2[ct2][r] + projB[co]) * mv;
      }
    }
  }
  __syncthreads();
  // ---- RQS spline on 32 lanes ----
  if (tid < 32){
    const float scv = 0.07216878364870323f;   // 1/sqrt(192)
    int tg = t0 + tid;
    float m = mrow[16+tid];
    float* z0p = z + ((size_t)b*2 + zs)*TTT + tg;
    float* z1p = z + ((size_t)b*2 + (1-zs))*TTT + tg;
    float xs = *z1p;
    float uw[10], uh[10], ud[9];
    #pragma unroll
    for (int k=0;k<10;k++) uw[k]=pro[tid*30+k]*scv;
    #pragma unroll
    for (int k=0;k<10;k++) uh[k]=pro[tid*30+10+k]*scv;
    #pragma unroll
    for (int k=0;k<9;k++)  ud[k]=pro[tid*30+20+k];
    bool inside = (xs >= -5.f) && (xs <= 5.f);
    float xc = fminf(fmaxf(xs,-5.f),5.f);
    float mx=uw[0];
    #pragma unroll
    for (int k=1;k<10;k++) mx=fmaxf(mx,uw[k]);
    float sw=0.f; float wd[10];
    #pragma unroll
    for (int k=0;k<10;k++){ wd[k]=__expf(uw[k]-mx); sw+=wd[k]; }
    float invw = 1.f/sw;
    #pragma unroll
    for (int k=0;k<10;k++) wd[k]=fmaf(0.99f*invw, wd[k], 1e-3f);
    float mh=uh[0];
    #pragma unroll
    for (int k=1;k<10;k++) mh=fmaxf(mh,uh[k]);
    float sh=0.f; float ht[10];
    #pragma unroll
    for (int k=0;k<10;k++){ ht[k]=__expf(uh[k]-mh); sh+=ht[k]; }
    float invh = 1.f/sh;
    #pragma unroll
    for (int k=0;k<10;k++) ht[k]=fmaf(0.99f*invh, ht[k], 1e-3f);
    float cw=-5.f, icw=-5.f, iw=1.f; int idx=0;
    #pragma unroll
    for (int i2=0;i2<10;i2++){
      float nw = (i2==9) ? 5.f : fmaf(10.f, wd[i2], cw);
      if (cw <= xc){ idx=i2; icw=cw; iw=nw-cw; }
      cw=nw;
    }
    float ch=-5.f, ich=-5.f, ih=1.f;
    #pragma unroll
    for (int i2=0;i2<10;i2++){
      float nh = (i2==9) ? 5.f : fmaf(10.f, ht[i2], ch);
      if (i2==idx){ ich=ch; ih=nh-ch; }
      ch=nh;
    }
    const float UDC = logf(expm1f(0.999f));
    float d0=1.f, d1=1.f;
    #pragma unroll
    for (int k=0;k<11;k++){
      float uu = (k==0 || k==10) ? UDC : ud[k-1];
      float dk = 1e-3f + softplus_f(uu);
      if (k==idx)   d0=dk;
      if (k==idx+1) d1=dk;
    }
    float idel = ih/iw;
    float th = (xc-icw)/iw;
    float t1m = th*(1.f-th);
    float den = idel + (d0+d1-2.f*idel)*t1m;
    float outv = ich + ih*(idel*th*th + d0*t1m)/den;
    float omt = 1.f-th;
    float dnum = idel*idel*(d1*th*th + 2.f*idel*t1m + d0*omt*omt);
    float lad = logf(dnum) - 2.f*logf(den);
    float y = inside ? outv : xs;
    lad = inside ? lad : 0.f;
    *z1p = y*m;
    *z0p = (*z0p)*m;
    float lm = lad*m;
    lm += __shfl_xor(lm, 1); lm += __shfl_xor(lm, 2);
    lm += __shfl_xor(lm, 4); lm += __shfl_xor(lm, 8);
    lm += __shfl_xor(lm, 16);
    if (tid == 0) atomicAdd(acco + b, -lm);
  }
}

// ---------------- z init ----------------
__global__ __launch_bounds__(256) void init_z_k(
    const float* __restrict__ e_q, const float* __restrict__ mask,
    const float* __restrict__ pm, const float* __restrict__ pl,
    float* __restrict__ z, float* __restrict__ acc){
  __shared__ float red[256];
  int b = blockIdx.y; int t = blockIdx.x*256 + threadIdx.x;
  float m = mask[(size_t)b*TTT + t];
  float pl0=pl[0], pl1=pl[1];
  float e0 = e_q[((size_t)b*2+0)*TTT + t]*m;
  float e1 = e_q[((size_t)b*2+1)*TTT + t]*m;
  z[((size_t)b*2+0)*TTT + t] = fmaf(__expf(pl0), e0, pm[0])*m;
  z[((size_t)b*2+1)*TTT + t] = fmaf(__expf(pl1), e1, pm[1])*m;
  float contrib = -0.5f*(LOG2PI_F + e0*e0)*m - 0.5f*(LOG2PI_F + e1*e1)*m - (pl0+pl1)*m;
  int tid = threadIdx.x;
  red[tid] = contrib;
  __syncthreads();
  for (int o=128;o>0;o>>=1){ if (tid<o) red[tid]+=red[tid+o]; __syncthreads(); }
  if (tid==0) atomicAdd(acc+b, red[0]);
}

// ---------------- between p-flows and f-flows ----------------
__global__ __launch_bounds__(256) void final_pre_k(
    float* __restrict__ z, const float* __restrict__ w_in, const float* __restrict__ mask,
    const float* __restrict__ am, const float* __restrict__ al, float* __restrict__ acc){
  __shared__ float red[256];
  int b = blockIdx.y; int t = blockIdx.x*256 + threadIdx.x;
  float m = mask[(size_t)b*TTT + t];
  float zu  = z[((size_t)b*2+0)*TTT + t];
  float z1v = z[((size_t)b*2+1)*TTT + t];
  float wv  = w_in[(size_t)b*TTT + t];
  float u  = m / (1.f + __expf(-zu));
  float z0 = (wv - u)*m;
  float y0 = logf(fmaxf(z0, 1e-5f))*m;
  float al0=al[0], al1=al[1];
  z[((size_t)b*2+0)*TTT + t] = fmaf(__expf(al0), y0,  am[0])*m;
  z[((size_t)b*2+1)*TTT + t] = fmaf(__expf(al1), z1v, am[1])*m;
  float contrib = -(logsig_f(zu)+logsig_f(-zu))*m + y0 - (al0+al1)*m;
  int tid = threadIdx.x;
  red[tid] = contrib;
  __syncthreads();
  for (int o=128;o>0;o>>=1){ if (tid<o) red[tid]+=red[tid+o]; __syncthreads(); }
  if (tid==0) atomicAdd(acc+b, red[0]);
}

// ---------------- final 0.5(log2pi + z^2) sum ----------------
__global__ __launch_bounds__(256) void final_post_k(
    const float* __restrict__ z, const float* __restrict__ mask, float* __restrict__ acc){
  __shared__ float red[256];
  int b = blockIdx.y; int t = blockIdx.x*256 + threadIdx.x;
  float m = mask[(size_t)b*TTT + t];
  float z0 = z[((size_t)b*2+0)*TTT + t];
  float z1 = z[((size_t)b*2+1)*TTT + t];
  float contrib = 0.5f*(LOG2PI_F + z0*z0)*m + 0.5f*(LOG2PI_F + z1*z1)*m;
  int tid = threadIdx.x;
  red[tid] = contrib;
  __syncthreads();
  for (int o=128;o>0;o>>=1){ if (tid<o) red[tid]+=red[tid+o]; __syncthreads(); }
  if (tid==0) atomicAdd(acc+b, red[0]);
}

__global__ void write_out_k(const float* __restrict__ acc, float* __restrict__ out, int n){
  int i = threadIdx.x;
  if (i < n) out[i] = acc[i];
}

extern "C" void kernel_launch(void* const* d_in, const int* in_sizes, int n_in,
                              void* d_out, int out_size, void* d_ws, size_t ws_size,
                              hipStream_t stream){
  (void)n_in; (void)out_size; (void)ws_size;
  const float* x         = (const float*)d_in[0];
  const float* mask      = (const float*)d_in[1];
  const float* w_in      = (const float*)d_in[2];
  const float* e_q       = (const float*)d_in[3];
  const float* pre_w     = (const float*)d_in[4];
  const float* pre_b     = (const float*)d_in[5];
  const float* proj_w    = (const float*)d_in[6];
  const float* proj_b    = (const float*)d_in[7];
  const float* dds_dep_w = (const float*)d_in[8];
  const float* dds_dep_b = (const float*)d_in[9];
  const float* dds_pw_w  = (const float*)d_in[10];
  const float* dds_pw_b  = (const float*)d_in[11];
  const float* dds_ln_g  = (const float*)d_in[12];
  const float* dds_ln_b  = (const float*)d_in[13];
  const float* post_pre_w  = (const float*)d_in[14];
  const float* post_pre_b  = (const float*)d_in[15];
  const float* post_proj_w = (const float*)d_in[16];
  const float* post_proj_b = (const float*)d_in[17];
  const float* pdds_dep_w  = (const float*)d_in[18];
  const float* pdds_dep_b  = (const float*)d_in[19];
  const float* pdds_pw_w   = (const float*)d_in[20];
  const float* pdds_pw_b   = (const float*)d_in[21];
  const float* pdds_ln_g   = (const float*)d_in[22];
  const float* pdds_ln_b   = (const float*)d_in[23];
  const float* aff_m    = (const float*)d_in[24];
  const float* aff_logs = (const float*)d_in[25];
  const float* f_pre_w  = (const float*)d_in[26];
  const float* f_pre_b  = (const float*)d_in[27];
  const float* f_dep_w  = (const float*)d_in[28];
  const float* f_dep_b  = (const float*)d_in[29];
  const float* f_pw_w   = (const float*)d_in[30];
  const float* f_pw_b   = (const float*)d_in[31];
  const float* f_ln_g   = (const float*)d_in[32];
  const float* f_ln_b   = (const float*)d_in[33];
  const float* f_proj_w = (const float*)d_in[34];
  const float* f_proj_b = (const float*)d_in[35];
  const float* paff_m    = (const float*)d_in[36];
  const float* paff_logs = (const float*)d_in[37];
  const float* p_pre_w  = (const float*)d_in[38];
  const float* p_pre_b  = (const float*)d_in[39];
  const float* p_dep_w  = (const float*)d_in[40];
  const float* p_dep_b  = (const float*)d_in[41];
  const float* p_pw_w   = (const float*)d_in[42];
  const float* p_pw_b   = (const float*)d_in[43];
  const float* p_ln_g   = (const float*)d_in[44];
  const float* p_ln_b   = (const float*)d_in[45];
  const float* p_proj_w = (const float*)d_in[46];
  const float* p_proj_b = (const float*)d_in[47];

  int Bn = in_sizes[0] / (CC*TTT);
  size_t big2 = (size_t)Bn*CC*TTT;
  unsigned short* xT = (unsigned short*)d_ws;
  unsigned short* A  = xT + big2;
  unsigned short* Bb = A  + big2;
  unsigned short* H  = Bb + big2;
  unsigned short* GP = H  + big2;
  unsigned short* Wb = GP + big2;
  size_t wtot = 33*(size_t)WSLOT + 8*(size_t)PSW;
  float* parP = (float*)(Wb + ((wtot + 7) & ~(size_t)7));
  float* zbuf = parP + 30*(size_t)PARL;
  float* acc  = zbuf + (size_t)Bn*2*TTT;

  hipMemsetAsync(acc, 0, Bn*sizeof(float), stream);
  convert_w_k<<<(int)((wtot + 255)/256), 256, 0, stream>>>(
      pre_w, proj_w, post_proj_w, dds_pw_w, pdds_pw_w, p_pw_w, f_pw_w,
      p_proj_w, f_proj_w, Wb);
  pack_par_k<<<(30*PARL + 255)/256, 256, 0, stream>>>(
      dds_dep_w, dds_dep_b, dds_ln_g, dds_ln_b, dds_pw_b,
      pdds_dep_w, pdds_dep_b, pdds_ln_g, pdds_ln_b, pdds_pw_b,
      p_dep_w, p_dep_b, p_ln_g, p_ln_b, p_pw_b,
      f_dep_w, f_dep_b, f_ln_g, f_ln_b, f_pw_b, parP);

  dim3 g32(TTT/32, Bn), g256(TTT/256, Bn);
  dim3 b256(256);

  unsigned short* W_pre      = Wb + 0*(size_t)WSLOT;
  unsigned short* W_proj     = Wb + 1*(size_t)WSLOT;
  unsigned short* W_postproj = Wb + 2*(size_t)WSLOT;
  unsigned short* W_dds      = Wb + 3*(size_t)WSLOT;
  unsigned short* W_pdds     = Wb + 6*(size_t)WSLOT;
  unsigned short* W_ppw      = Wb + 9*(size_t)WSLOT;
  unsigned short* W_fpw      = Wb + 21*(size_t)WSLOT;
  unsigned short* W_pproj    = Wb + 33*(size_t)WSLOT;
  unsigned short* W_fproj    = W_pproj + 4*(size_t)PSW;

  transpose_x_k<<<g32, b256, 0, stream>>>(x, xT);

  // ---- h path (param set 0) ----
  conv_cc_k<<<g32, b256, 0, stream>>>(xT, W_pre, pre_b, mask, nullptr, A, 0);
  mega_dds_k<<<g32, b256, 0, stream>>>(A, nullptr, 0, nullptr, Bb, mask,
      parP + 0*(size_t)3*PARL, nullptr, nullptr,
      W_dds, 0, 0, nullptr, nullptr, nullptr, 0, acc);
  conv_cc_k<<<g32, b256, 0, stream>>>(Bb, W_proj, proj_b, mask, nullptr, H, 1);

  // ---- hw path (param set 1) ----
  mega_dds_k<<<g32, b256, 0, stream>>>(nullptr, w_in, TTT, nullptr, A, mask,
      parP + 1*(size_t)3*PARL, post_pre_w, post_pre_b,
      W_pdds, 1, 0, nullptr, nullptr, nullptr, 0, acc);
  conv_cc_k<<<g32, b256, 0, stream>>>(A, W_postproj, post_proj_b, mask, H, GP, 2);

  // ---- init z ----
  init_z_k<<<g256, b256, 0, stream>>>(e_q, mask, paff_m, paff_logs, zbuf, acc);

  // ---- 4 posterior flows (g = GP, param sets 2..5) ----
  for (int f=0; f<4; f++){
    int s = f & 1;
    mega_dds_k<<<g32, b256, 0, stream>>>(nullptr, zbuf + (size_t)s*TTT, 2*TTT, GP, nullptr, mask,
        parP + (size_t)(2+f)*3*PARL,
        p_pre_w + (size_t)f*CC, p_pre_b + (size_t)f*CC,
        W_ppw + (size_t)f*3*WSLOT, 1, 1,
        W_pproj + (size_t)f*PSW, p_proj_b + (size_t)f*PP, zbuf, s, acc);
  }

  // ---- transition ----
  final_pre_k<<<g256, b256, 0, stream>>>(zbuf, w_in, mask, aff_m, aff_logs, acc);

  // ---- 4 flows (g = H, param sets 6..9) ----
  for (int f=0; f<4; f++){
    int s = f & 1;
    mega_dds_k<<<g32, b256, 0, stream>>>(nullptr, zbuf + (size_t)s*TTT, 2*TTT, H, nullptr, mask,
        parP + (size_t)(6+f)*3*PARL,
        f_pre_w + (size_t)f*CC, f_pre_b + (size_t)f*CC,
        W_fpw + (size_t)f*3*WSLOT, 1, 1,
        W_fproj + (size_t)f*PSW, f_proj_b + (size_t)f*PP, zbuf, s, acc);
  }

  final_post_k<<<g256, b256, 0, stream>>>(zbuf, mask, acc);
  write_out_k<<<1, 64, 0, stream>>>(acc, (float*)d_out, Bn);
}

// Round 10
// 745.007 us; speedup vs baseline: 1.5728x; 1.0423x over previous
//
#include <hip/hip_runtime.h>
#include <math.h>

#define CC 192
#define TTT 768
#define PP 29
#define LOG2PI_F 1.8378770664093453f
#define WSLOT 36864   // swizzled 192x192 slot (elements)
#define PSW 6144      // swizzled 32x192 proj slot (elements)
#define XS 200        // ushort stride for conv_cc/transpose LDS tiles
#define XSP 200       // ushort stride for mega ping (400B rows: 16B-aligned, 2-way bank alias = free)
#define PARL 1728     // 9*192 floats per layer param block

typedef __attribute__((ext_vector_type(8))) short short8;
typedef __attribute__((ext_vector_type(4))) float floatx4;
typedef __attribute__((ext_vector_type(2))) float float2v;
union Frag { int4 i; short8 s; };

__device__ __forceinline__ float2v fma2(float2v a, float2v b, float2v c){
  return __builtin_elementwise_fma(a, b, c);
}
__device__ __forceinline__ float geluf(float x){
  float u = 1.5957691216057308f * (x + 0.044715f*x*x*x);
  return x * __builtin_amdgcn_rcpf(1.f + __expf(-u));
}
__device__ __forceinline__ float softplus_f(float x){
  return (x > 20.f) ? x : log1pf(__expf(x));
}
__device__ __forceinline__ float logsig_f(float x){
  return -softplus_f(-x);
}
__device__ __forceinline__ unsigned short f2bf(float f){
  unsigned int u = __builtin_bit_cast(unsigned int, f);
  u += 0x7fffu + ((u >> 16) & 1u);
  return (unsigned short)(u >> 16);
}
__device__ __forceinline__ unsigned int packbf2(float a0, float a1){
  return (unsigned int)f2bf(a0) | ((unsigned int)f2bf(a1) << 16);
}
__device__ __forceinline__ void unbf2(unsigned int u, float& lo, float& hi){
  lo = __builtin_bit_cast(float, u << 16);
  hi = __builtin_bit_cast(float, u & 0xffff0000u);
}
__device__ __forceinline__ float2v unbf2v(unsigned int u){
  float2v r;
  r.x = __builtin_bit_cast(float, u << 16);
  r.y = __builtin_bit_cast(float, u & 0xffff0000u);
  return r;
}
__device__ __forceinline__ void unp8(int4 v, float* o){
  unsigned int* p = (unsigned int*)&v;
  unbf2(p[0], o[0], o[1]); unbf2(p[1], o[2], o[3]);
  unbf2(p[2], o[4], o[5]); unbf2(p[3], o[6], o[7]);
}
__device__ __forceinline__ void f4arr(float4 v, float* o){ o[0]=v.x;o[1]=v.y;o[2]=v.z;o[3]=v.w; }
__device__ __forceinline__ float2v pick2(float4 a, float4 b, int p){
  switch(p){
    case 0: return (float2v){a.x, a.y};
    case 1: return (float2v){a.z, a.w};
    case 2: return (float2v){b.x, b.y};
    default: return (float2v){b.z, b.w};
  }
}

// ---------------- weight f32 -> bf16 swizzled fragment order ----------------
__global__ __launch_bounds__(256) void convert_w_k(
    const float* __restrict__ p0, const float* __restrict__ p1,
    const float* __restrict__ p2, const float* __restrict__ p3,
    const float* __restrict__ p4, const float* __restrict__ p5,
    const float* __restrict__ p6, const float* __restrict__ p7,
    const float* __restrict__ p8, unsigned short* __restrict__ Wb){
  int i = blockIdx.x*256 + threadIdx.x;
  const int totalA = 33*WSLOT;
  const int total = totalA + 8*PSW;
  if (i >= total) return;
  if (i < totalA){
    int slot = i / WSLOT, j = i % WSLOT;
    int e = j & 7, lane = (j>>3) & 63, kt = j >> 9;
    int k = kt % 6, tile = kt / 6;
    int co = tile*16 + (lane & 15);
    int kk = k*32 + (lane>>4)*8 + e;
    int r = co*CC + kk;
    const float* src;
    if      (slot == 0) src = p0 + r;
    else if (slot == 1) src = p1 + r;
    else if (slot == 2) src = p2 + r;
    else if (slot < 6)  src = p3 + (size_t)(slot-3)*WSLOT + r;
    else if (slot < 9)  src = p4 + (size_t)(slot-6)*WSLOT + r;
    else if (slot < 21) src = p5 + (size_t)(slot-9)*WSLOT + r;
    else                src = p6 + (size_t)(slot-21)*WSLOT + r;
    Wb[i] = f2bf(*src);
  } else {
    int r2 = i - totalA;
    int ps = r2 / PSW, j = r2 % PSW;
    int e = j & 7, lane = (j>>3) & 63, kt = j >> 9;
    int k = kt % 6, tile = kt / 6;
    int co = tile*16 + (lane & 15); if (co > PP-1) co = PP-1;
    int kk = k*32 + (lane>>4)*8 + e;
    const float* base = (ps < 4) ? (p7 + (size_t)ps*PP*CC) : (p8 + (size_t)(ps-4)*PP*CC);
    Wb[i] = f2bf(base[co*CC + kk]);
  }
}

// ---------------- per-layer params -> [set][layer][9][192] f32 ----------------
__global__ __launch_bounds__(256) void pack_par_k(
    const float* __restrict__ dds_dep_w, const float* __restrict__ dds_dep_b,
    const float* __restrict__ dds_ln_g,  const float* __restrict__ dds_ln_b,
    const float* __restrict__ dds_pw_b,
    const float* __restrict__ pdds_dep_w, const float* __restrict__ pdds_dep_b,
    const float* __restrict__ pdds_ln_g,  const float* __restrict__ pdds_ln_b,
    const float* __restrict__ pdds_pw_b,
    const float* __restrict__ p_dep_w, const float* __restrict__ p_dep_b,
    const float* __restrict__ p_ln_g,  const float* __restrict__ p_ln_b,
    const float* __restrict__ p_pw_b,
    const float* __restrict__ f_dep_w, const float* __restrict__ f_dep_b,
    const float* __restrict__ f_ln_g,  const float* __restrict__ f_ln_b,
    const float* __restrict__ f_pw_b,
    float* __restrict__ P){
  int i = blockIdx.x*256 + threadIdx.x;
  const int total = 30*PARL;
  if (i >= total) return;
  int ls = i / PARL, r = i % PARL;
  int arr = r / 192, c = r % 192;
  const float *dep_w, *dep_b, *ln_g, *ln_b, *pw_b;
  int l;
  if (ls < 3){
    l = ls; dep_w = dds_dep_w; dep_b = dds_dep_b; ln_g = dds_ln_g; ln_b = dds_ln_b; pw_b = dds_pw_b;
  } else if (ls < 6){
    l = ls-3; dep_w = pdds_dep_w; dep_b = pdds_dep_b; ln_g = pdds_ln_g; ln_b = pdds_ln_b; pw_b = pdds_pw_b;
  } else if (ls < 18){
    int f = (ls-6)/3; l = (ls-6)%3;
    dep_w = p_dep_w + (size_t)f*3*CC*3; dep_b = p_dep_b + (size_t)f*3*CC;
    ln_g = p_ln_g + (size_t)f*3*2*CC;  ln_b = p_ln_b + (size_t)f*3*2*CC;
    pw_b = p_pw_b + (size_t)f*3*CC;
  } else {
    int f = (ls-18)/3; l = (ls-18)%3;
    dep_w = f_dep_w + (size_t)f*3*CC*3; dep_b = f_dep_b + (size_t)f*3*CC;
    ln_g = f_ln_g + (size_t)f*3*2*CC;  ln_b = f_ln_b + (size_t)f*3*2*CC;
    pw_b = f_pw_b + (size_t)f*3*CC;
  }
  float v;
  if      (arr < 3)  v = dep_w[((size_t)l*CC + c)*3 + arr];
  else if (arr == 3) v = dep_b[(size_t)l*CC + c];
  else if (arr == 4) v = ln_g[((size_t)l*2+0)*CC + c];
  else if (arr == 5) v = ln_b[((size_t)l*2+0)*CC + c];
  else if (arr == 6) v = ln_g[((size_t)l*2+1)*CC + c];
  else if (arr == 7) v = ln_b[((size_t)l*2+1)*CC + c];
  else               v = pw_b[(size_t)l*CC + c];
  P[i] = v;
}

// ---------------- x f32 [B][C][T] -> bf16 [B][T][C] ----------------
__global__ __launch_bounds__(256) void transpose_x_k(
    const float* __restrict__ x, unsigned short* __restrict__ xT){
  __shared__ unsigned short tile[32*XS];
  int b = blockIdx.y, t0 = blockIdx.x*32, tid = threadIdx.x;
  int tl4 = (tid & 7)*4, cr = tid >> 3;
  #pragma unroll
  for (int rnd=0; rnd<6; rnd++){
    int c = rnd*32 + cr;
    float4 v4 = *(const float4*)(x + ((size_t)b*CC + c)*TTT + t0 + tl4);
    tile[(tl4+0)*XS + c] = f2bf(v4.x);
    tile[(tl4+1)*XS + c] = f2bf(v4.y);
    tile[(tl4+2)*XS + c] = f2bf(v4.z);
    tile[(tl4+3)*XS + c] = f2bf(v4.w);
  }
  __syncthreads();
  #pragma unroll
  for (int k=0;k<3;k++){
    int task = k*256 + tid;
    int row = task/24, cn = task%24;
    *(int4*)(xT + ((size_t)b*TTT + t0 + row)*CC + cn*8) = *(const int4*)&tile[row*XS + cn*8];
  }
}

// ---------------- conv 192x192 bf16 MFMA, t-major bf16 in/out ----------------
__global__ __launch_bounds__(256) void conv_cc_k(
    const unsigned short* __restrict__ in, const unsigned short* __restrict__ Wsw,
    const float* __restrict__ bias, const float* __restrict__ mask,
    const unsigned short* __restrict__ addsrc, unsigned short* __restrict__ outb, int mode){
  __shared__ unsigned short bufX[32*XS];
  __shared__ unsigned short bufY[32*XS];
  __shared__ float marr[32];
  int b = blockIdx.y, t0 = blockIdx.x*32, tid = threadIdx.x;
  #pragma unroll
  for (int k=0;k<3;k++){
    int task = k*256 + tid;
    int row = task/24, cn = task%24;
    const unsigned short* src = in + ((size_t)b*TTT + t0 + row)*CC + cn*8;
    *(int4*)&bufX[row*XS + cn*8] = *(const int4*)src;
    if (mode == 2){
      const unsigned short* s2 = addsrc + ((size_t)b*TTT + t0 + row)*CC + cn*8;
      *(int4*)&bufY[row*XS + cn*8] = *(const int4*)s2;
    }
  }
  if (tid >= 128 && tid < 160) marr[tid-128] = mask[(size_t)b*TTT + t0 + (tid-128)];
  __syncthreads();
  int w = tid >> 6, lane = tid & 63;
  int n16 = lane & 15, quad = lane >> 4;
  Frag af[3][6];
  #pragma unroll
  for (int ct=0; ct<3; ct++){
    int tile = w*3 + ct;
    #pragma unroll
    for (int k=0;k<6;k++)
      af[ct][k].i = *(const int4*)(Wsw + ((size_t)(tile*6 + k)*64 + lane)*8);
  }
  floatx4 acc[3][2];
  #pragma unroll
  for (int ct=0;ct<3;ct++)
    #pragma unroll
    for (int tt=0;tt<2;tt++)
      acc[ct][tt] = (floatx4){0.f,0.f,0.f,0.f};
  #pragma unroll
  for (int k=0;k<6;k++){
    Frag bf[2];
    #pragma unroll
    for (int tt=0;tt<2;tt++)
      bf[tt].i = *(const int4*)&bufX[(tt*16+n16)*XS + k*32 + quad*8];
    #pragma unroll
    for (int ct=0;ct<3;ct++)
      #pragma unroll
      for (int tt=0;tt<2;tt++)
        acc[ct][tt] = __builtin_amdgcn_mfma_f32_16x16x32_bf16(af[ct][k].s, bf[tt].s, acc[ct][tt], 0,0,0);
  }
  __syncthreads();
  #pragma unroll
  for (int ct=0;ct<3;ct++){
    int cobase = w*48 + ct*16 + quad*4;
    float4 b4 = *(const float4*)(bias + cobase);
    float ba[4] = {b4.x, b4.y, b4.z, b4.w};
    #pragma unroll
    for (int tt=0;tt<2;tt++){
      int t = tt*16 + n16;
      float mv = (mode >= 1) ? marr[t] : 1.f;
      float av[4] = {0.f,0.f,0.f,0.f};
      if (mode == 2){
        uint2 uy = *(uint2*)&bufY[t*XS + cobase];
        unbf2(uy.x, av[0], av[1]); unbf2(uy.y, av[2], av[3]);
      }
      float hh[4];
      #pragma unroll
      for (int r=0;r<4;r++){
        float v = acc[ct][tt][r] + ba[r];
        if (mode >= 1) v *= mv;
        if (mode == 2) v += av[r];
        hh[r] = v;
      }
      uint2 wv; wv.x = packbf2(hh[0], hh[1]); wv.y = packbf2(hh[2], hh[3]);
      *(uint2*)&bufX[t*XS + cobase] = wv;
    }
  }
  __syncthreads();
  #pragma unroll
  for (int k=0;k<3;k++){
    int task = k*256 + tid;
    int row = task/24, cn = task%24;
    *(int4*)(outb + ((size_t)b*TTT + t0 + row)*CC + cn*8) = *(const int4*)&bufX[row*XS + cn*8];
  }
}

// ---------------- mega DDS v5: bf16 ping(16B rows) + LDS params + A prefetch ----------------
// NOTE: assumes binary mask (m*m == m): stream is kept pre-masked; P6 applies the
// row mask to the updated row so the depthwise needs no tap masks.
__global__ __launch_bounds__(256,3) void mega_dds_k(
    const unsigned short* __restrict__ in,
    const float* __restrict__ zsrc, int zstride,
    const unsigned short* __restrict__ g,
    unsigned short* __restrict__ outb,
    const float* __restrict__ mask,
    const float* __restrict__ parP,     // 3 layers x PARL floats
    const float* __restrict__ pw1, const float* __restrict__ pb1,
    const unsigned short* __restrict__ Wsw,
    int srcmode, int outmode,
    const unsigned short* __restrict__ projW, const float* __restrict__ projB,
    float* __restrict__ z, int zs, float* __restrict__ acco){
  __shared__ unsigned short ping[64*XSP];   // bf16 [window row][c], masked residual stream
  __shared__ float par[2][PARL];            // per-layer params, double-buffered
  __shared__ float mrow[64];
  float* pro = par[0];                      // alias: used only after all layers done

  int b = blockIdx.y, t0 = blockIdx.x*32, tid = threadIdx.x;
  int ws0 = t0 - 16;
  int w = tid >> 6, lane = tid & 63;
  int n16 = lane & 15, quad = lane >> 4;
  int row = w*16 + n16;                      // this lane's window row
  const float* mkb = mask + (size_t)b*TTT;
  const int dils[3] = {1,3,9};

  if (tid < 64){
    int gt = ws0 + tid;
    bool inr = (gt >= 0) && (gt < TTT);
    int gc = gt < 0 ? 0 : (gt > TTT-1 ? TTT-1 : gt);
    mrow[tid] = inr ? mkb[gc] : 0.f;
  }
  // stage layer-0 params
  #pragma unroll
  for (int k=0;k<7;k++){
    int i2 = k*256 + tid;
    if (i2 < PARL) par[0][i2] = parP[i2];
  }
  // ---- staging (pre-masked) ----
  if (srcmode == 0){
    #pragma unroll
    for (int k=0;k<6;k++){
      int task = k*256 + tid;
      int r = task/24, cn = task%24, c0 = cn*8;
      int gt = ws0 + r;
      bool inr = (gt >= 0) && (gt < TTT);
      int gc = gt < 0 ? 0 : (gt > TTT-1 ? TTT-1 : gt);
      float mv = inr ? mkb[gc] : 0.f;
      float hv[8];
      unp8(*(const int4*)(in + ((size_t)b*TTT + gc)*CC + c0), hv);
      int4 pk;
      pk.x = (int)packbf2(hv[0]*mv, hv[1]*mv); pk.y = (int)packbf2(hv[2]*mv, hv[3]*mv);
      pk.z = (int)packbf2(hv[4]*mv, hv[5]*mv); pk.w = (int)packbf2(hv[6]*mv, hv[7]*mv);
      *(int4*)&ping[r*XSP + c0] = pk;
    }
  } else {
    #pragma unroll
    for (int k=0;k<6;k++){
      int task = k*256 + tid;
      int r = task/24, cn = task%24, c0 = cn*8;
      int gt = ws0 + r;
      bool inr = (gt >= 0) && (gt < TTT);
      int gc = gt < 0 ? 0 : (gt > TTT-1 ? TTT-1 : gt);
      float mv = inr ? mkb[gc] : 0.f;
      float zv = inr ? zsrc[(size_t)b*zstride + gc] : 0.f;
      float hv[8];
      if (g){
        unp8(*(const int4*)(g + ((size_t)b*TTT + gc)*CC + c0), hv);
      } else {
        #pragma unroll
        for (int e=0;e<8;e++) hv[e] = 0.f;
      }
      float4 pwa = *(const float4*)(pw1 + c0);
      float4 pwb2 = *(const float4*)(pw1 + c0 + 4);
      float4 pba = *(const float4*)(pb1 + c0);
      float4 pbb2 = *(const float4*)(pb1 + c0 + 4);
      float pwv[8], pbv[8];
      f4arr(pwa, pwv); f4arr(pwb2, pwv+4);
      f4arr(pba, pbv); f4arr(pbb2, pbv+4);
      float ov[8];
      #pragma unroll
      for (int e=0;e<8;e++) ov[e] = (hv[e] + fmaf(pwv[e], zv, pbv[e]))*mv;
      int4 pk;
      pk.x = (int)packbf2(ov[0], ov[1]); pk.y = (int)packbf2(ov[2], ov[3]);
      pk.z = (int)packbf2(ov[4], ov[5]); pk.w = (int)packbf2(ov[6], ov[7]);
      *(int4*)&ping[r*XSP + c0] = pk;
    }
  }
  __syncthreads();

  // ---- 3 fused layers ----
  #pragma unroll
  for (int l=0; l<3; l++){
    const int dil = dils[l];
    const bool active = (l < 2) || (w == 1) || (w == 2);
    const float* pl = par[l & 1];
    Frag bfr[6];
    floatx4 acc[12];
    if (active){
      int iL = row - dil; iL = iL < 0 ? 0 : iL;
      int iR = row + dil; iR = iR > 63 ? 63 : iR;
      float2v vv[24];
      float2v s2v = {0.f,0.f}, q2v = {0.f,0.f};
      #pragma unroll
      for (int j=0;j<6;j++){
        int kk = j*32 + quad*8;
        int4 L4 = *(const int4*)&ping[iL*XSP + kk];
        int4 C4 = *(const int4*)&ping[row*XSP + kk];
        int4 R4 = *(const int4*)&ping[iR*XSP + kk];
        unsigned int* Lp = (unsigned int*)&L4;
        unsigned int* Cp = (unsigned int*)&C4;
        unsigned int* Rp = (unsigned int*)&R4;
        float4 w0a = *(const float4*)&pl[kk],       w0b = *(const float4*)&pl[kk+4];
        float4 w1a = *(const float4*)&pl[192+kk],   w1b = *(const float4*)&pl[192+kk+4];
        float4 w2a = *(const float4*)&pl[384+kk],   w2b = *(const float4*)&pl[384+kk+4];
        float4 dba = *(const float4*)&pl[576+kk],   dbb = *(const float4*)&pl[576+kk+4];
        #pragma unroll
        for (int p=0;p<4;p++){
          float2v val = fma2(pick2(w0a,w0b,p), unbf2v(Lp[p]),
                        fma2(pick2(w1a,w1b,p), unbf2v(Cp[p]),
                        fma2(pick2(w2a,w2b,p), unbf2v(Rp[p]), pick2(dba,dbb,p))));
          vv[j*4+p] = val;
          s2v += val;
          q2v = fma2(val, val, q2v);
        }
      }
      float s = s2v.x + s2v.y, q = q2v.x + q2v.y;
      s += __shfl_xor(s, 16); s += __shfl_xor(s, 32);
      q += __shfl_xor(q, 16); q += __shfl_xor(q, 32);
      float mm = s*(1.f/CC);
      float rr = rsqrtf(q*(1.f/CC) - mm*mm + 1e-5f);
      // P3: LN + gelu -> B fragments in registers
      {
        float2v mm2 = {mm,mm}, rr2 = {rr,rr};
        #pragma unroll
        for (int j=0;j<6;j++){
          int kk = j*32 + quad*8;
          float4 g0a = *(const float4*)&pl[768+kk], g0b = *(const float4*)&pl[768+kk+4];
          float4 b0a = *(const float4*)&pl[960+kk], b0b = *(const float4*)&pl[960+kk+4];
          unsigned int wwp[4];
          #pragma unroll
          for (int p=0;p<4;p++){
            float2v a = fma2((vv[j*4+p]-mm2)*rr2, pick2(g0a,g0b,p), pick2(b0a,b0b,p));
            wwp[p] = packbf2(geluf(a.x), geluf(a.y));
          }
          bfr[j].i = make_int4((int)wwp[0], (int)wwp[1], (int)wwp[2], (int)wwp[3]);
        }
      }
    }
    __syncthreads();   // all P1 ping reads done before in-place P6 writes
    // stage next layer's params (overlaps P4; visible at end-of-layer barrier)
    if (l < 2){
      const float* src = parP + (size_t)(l+1)*PARL;
      #pragma unroll
      for (int k=0;k<7;k++){
        int i2 = k*256 + tid;
        if (i2 < PARL) par[(l+1)&1][i2] = src[i2];
      }
    }
    if (active){
      // P4: stream 12 A-tiles with software double-buffer, B from registers
      const unsigned short* WL = Wsw + (size_t)l*WSLOT;
      Frag afb[2][6];
      #pragma unroll
      for (int k=0;k<6;k++)
        afb[0][k].i = *(const int4*)(WL + ((size_t)(0*6 + k)*64 + lane)*8);
      #pragma unroll
      for (int tile=0; tile<12; tile++){
        int cur = tile & 1, nxt = cur ^ 1;
        if (tile < 11){
          #pragma unroll
          for (int k=0;k<6;k++)
            afb[nxt][k].i = *(const int4*)(WL + ((size_t)((tile+1)*6 + k)*64 + lane)*8);
        }
        acc[tile] = (floatx4){0.f,0.f,0.f,0.f};
        #pragma unroll
        for (int k=0;k<6;k++)
          acc[tile] = __builtin_amdgcn_mfma_f32_16x16x32_bf16(afb[cur][k].s, bfr[k].s, acc[tile], 0,0,0);
      }
      // bias + conv-LN stats (packed, in-wave)
      float2v s2p = {0.f,0.f}, q2p = {0.f,0.f};
      #pragma unroll
      for (int tile=0; tile<12; tile++){
        int co = tile*16 + quad*4;
        float4 pbv = *(const float4*)&pl[1536+co];
        acc[tile][0] += pbv.x; acc[tile][1] += pbv.y;
        acc[tile][2] += pbv.z; acc[tile][3] += pbv.w;
        float2v v01 = {acc[tile][0], acc[tile][1]};
        float2v v23 = {acc[tile][2], acc[tile][3]};
        s2p += v01 + v23;
        q2p = fma2(v01, v01, q2p);
        q2p = fma2(v23, v23, q2p);
      }
      float s2 = s2p.x + s2p.y, q2 = q2p.x + q2p.y;
      s2 += __shfl_xor(s2, 16); s2 += __shfl_xor(s2, 32);
      q2 += __shfl_xor(q2, 16); q2 += __shfl_xor(q2, 32);
      float cmP = s2*(1.f/CC);
      float crP = rsqrtf(q2*(1.f/CC) - cmP*cmP + 1e-5f);
      // P6: LN + gelu + residual, apply row mask, in-place
      float mc = mrow[row];
      float2v mc2 = {mc,mc};
      float2v cm2 = {cmP,cmP}, cr2 = {crP,crP};
      #pragma unroll
      for (int tile=0; tile<12; tile++){
        int co = tile*16 + quad*4;
        float4 g1v = *(const float4*)&pl[1152+co];
        float4 b1v = *(const float4*)&pl[1344+co];
        uint2 ux = *(uint2*)&ping[row*XSP + co];
        float2v x01 = unbf2v(ux.x), x23 = unbf2v(ux.y);
        float2v v01 = {acc[tile][0], acc[tile][1]};
        float2v v23 = {acc[tile][2], acc[tile][3]};
        float2v a01 = fma2((v01-cm2)*cr2, (float2v){g1v.x,g1v.y}, (float2v){b1v.x,b1v.y});
        float2v a23 = fma2((v23-cm2)*cr2, (float2v){g1v.z,g1v.w}, (float2v){b1v.z,b1v.w});
        float2v h01 = (x01 + (float2v){geluf(a01.x), geluf(a01.y)}) * mc2;
        float2v h23 = (x23 + (float2v){geluf(a23.x), geluf(a23.y)}) * mc2;
        uint2 wv;
        wv.x = packbf2(h01.x, h01.y);
        wv.y = packbf2(h23.x, h23.y);
        *(uint2*)&ping[row*XSP + co] = wv;
      }
    }
    __syncthreads();   // P6 writes + par staging visible
  }

  if (outmode == 0){
    #pragma unroll
    for (int k=0;k<3;k++){
      int task = k*256 + tid;
      int r = task/24, cn = task%24, c0 = cn*8;
      *(int4*)(outb + ((size_t)b*TTT + t0 + r)*CC + c0) = *(const int4*)&ping[(16+r)*XSP + c0];
    }
    return;
  }

  // ---- proj (29x192) on center rows: waves 1,2 own rows 16..47 ----
  if (w == 1 || w == 2){
    Frag bfp[6];
    #pragma unroll
    for (int k=0;k<6;k++)
      bfp[k].i = *(const int4*)&ping[row*XSP + k*32 + quad*8];
    floatx4 acc2[2];
    acc2[0] = (floatx4){0.f,0.f,0.f,0.f};
    acc2[1] = (floatx4){0.f,0.f,0.f,0.f};
    #pragma unroll
    for (int ct2=0; ct2<2; ct2++){
      #pragma unroll
      for (int k=0;k<6;k++){
        Frag af;
        af.i = *(const int4*)(projW + ((size_t)(ct2*6 + k)*64 + lane)*8);
        acc2[ct2] = __builtin_amdgcn_mfma_f32_16x16x32_bf16(af.s, bfp[k].s, acc2[ct2], 0,0,0);
      }
    }
    int rt = row - 16;                  // 0..31
    float mv = mrow[row];
    #pragma unroll
    for (int ct2=0; ct2<2; ct2++){
      int cobase = ct2*16 + quad*4;
      #pragma unroll
      for (int r=0;r<4;r++){
        int co = cobase + r;
        if (co < PP) pro[rt*30 + co] = (acc2[ct2][r] + projB[co]) * mv;
      }
    }
  }
  __syncthreads();
  // ---- RQS spline on 32 lanes ----
  if (tid < 32){
    const float scv = 0.07216878364870323f;   // 1/sqrt(192)
    int tg = t0 + tid;
    float m = mrow[16+tid];
    float* z0p = z + ((size_t)b*2 + zs)*TTT + tg;
    float* z1p = z + ((size_t)b*2 + (1-zs))*TTT + tg;
    float xs = *z1p;
    float uw[10], uh[10], ud[9];
    #pragma unroll
    for (int k=0;k<10;k++) uw[k]=pro[tid*30+k]*scv;
    #pragma unroll
    for (int k=0;k<10;k++) uh[k]=pro[tid*30+10+k]*scv;
    #pragma unroll
    for (int k=0;k<9;k++)  ud[k]=pro[tid*30+20+k];
    bool inside = (xs >= -5.f) && (xs <= 5.f);
    float xc = fminf(fmaxf(xs,-5.f),5.f);
    float mx=uw[0];
    #pragma unroll
    for (int k=1;k<10;k++) mx=fmaxf(mx,uw[k]);
    float sw=0.f; float wd[10];
    #pragma unroll
    for (int k=0;k<10;k++){ wd[k]=__expf(uw[k]-mx); sw+=wd[k]; }
    float invw = 1.f/sw;
    #pragma unroll
    for (int k=0;k<10;k++) wd[k]=fmaf(0.99f*invw, wd[k], 1e-3f);
    float mh=uh[0];
    #pragma unroll
    for (int k=1;k<10;k++) mh=fmaxf(mh,uh[k]);
    float sh=0.f; float ht[10];
    #pragma unroll
    for (int k=0;k<10;k++){ ht[k]=__expf(uh[k]-mh); sh+=ht[k]; }
    float invh = 1.f/sh;
    #pragma unroll
    for (int k=0;k<10;k++) ht[k]=fmaf(0.99f*invh, ht[k], 1e-3f);
    float cw=-5.f, icw=-5.f, iw=1.f; int idx=0;
    #pragma unroll
    for (int i2=0;i2<10;i2++){
      float nw = (i2==9) ? 5.f : fmaf(10.f, wd[i2], cw);
      if (cw <= xc){ idx=i2; icw=cw; iw=nw-cw; }
      cw=nw;
    }
    float ch=-5.f, ich=-5.f, ih=1.f;
    #pragma unroll
    for (int i2=0;i2<10;i2++){
      float nh = (i2==9) ? 5.f : fmaf(10.f, ht[i2], ch);
      if (i2==idx){ ich=ch; ih=nh-ch; }
      ch=nh;
    }
    const float UDC = logf(expm1f(0.999f));
    float d0=1.f, d1=1.f;
    #pragma unroll
    for (int k=0;k<11;k++){
      float uu = (k==0 || k==10) ? UDC : ud[k-1];
      float dk = 1e-3f + softplus_f(uu);
      if (k==idx)   d0=dk;
      if (k==idx+1) d1=dk;
    }
    float idel = ih/iw;
    float th = (xc-icw)/iw;
    float t1m = th*(1.f-th);
    float den = idel + (d0+d1-2.f*idel)*t1m;
    float outv = ich + ih*(idel*th*th + d0*t1m)/den;
    float omt = 1.f-th;
    float dnum = idel*idel*(d1*th*th + 2.f*idel*t1m + d0*omt*omt);
    float lad = logf(dnum) - 2.f*logf(den);
    float y = inside ? outv : xs;
    lad = inside ? lad : 0.f;
    *z1p = y*m;
    *z0p = (*z0p)*m;
    float lm = lad*m;
    lm += __shfl_xor(lm, 1); lm += __shfl_xor(lm, 2);
    lm += __shfl_xor(lm, 4); lm += __shfl_xor(lm, 8);
    lm += __shfl_xor(lm, 16);
    if (tid == 0) atomicAdd(acco + b, -lm);
  }
}

// ---------------- z init ----------------
__global__ __launch_bounds__(256) void init_z_k(
    const float* __restrict__ e_q, const float* __restrict__ mask,
    const float* __restrict__ pm, const float* __restrict__ pl,
    float* __restrict__ z, float* __restrict__ acc){
  __shared__ float red[256];
  int b = blockIdx.y; int t = blockIdx.x*256 + threadIdx.x;
  float m = mask[(size_t)b*TTT + t];
  float pl0=pl[0], pl1=pl[1];
  float e0 = e_q[((size_t)b*2+0)*TTT + t]*m;
  float e1 = e_q[((size_t)b*2+1)*TTT + t]*m;
  z[((size_t)b*2+0)*TTT + t] = fmaf(__expf(pl0), e0, pm[0])*m;
  z[((size_t)b*2+1)*TTT + t] = fmaf(__expf(pl1), e1, pm[1])*m;
  float contrib = -0.5f*(LOG2PI_F + e0*e0)*m - 0.5f*(LOG2PI_F + e1*e1)*m - (pl0+pl1)*m;
  int tid = threadIdx.x;
  red[tid] = contrib;
  __syncthreads();
  for (int o=128;o>0;o>>=1){ if (tid<o) red[tid]+=red[tid+o]; __syncthreads(); }
  if (tid==0) atomicAdd(acc+b, red[0]);
}

// ---------------- between p-flows and f-flows ----------------
__global__ __launch_bounds__(256) void final_pre_k(
    float* __restrict__ z, const float* __restrict__ w_in, const float* __restrict__ mask,
    const float* __restrict__ am, const float* __restrict__ al, float* __restrict__ acc){
  __shared__ float red[256];
  int b = blockIdx.y; int t = blockIdx.x*256 + threadIdx.x;
  float m = mask[(size_t)b*TTT + t];
  float zu  = z[((size_t)b*2+0)*TTT + t];
  float z1v = z[((size_t)b*2+1)*TTT + t];
  float wv  = w_in[(size_t)b*TTT + t];
  float u  = m / (1.f + __expf(-zu));
  float z0 = (wv - u)*m;
  float y0 = logf(fmaxf(z0, 1e-5f))*m;
  float al0=al[0], al1=al[1];
  z[((size_t)b*2+0)*TTT + t] = fmaf(__expf(al0), y0,  am[0])*m;
  z[((size_t)b*2+1)*TTT + t] = fmaf(__expf(al1), z1v, am[1])*m;
  float contrib = -(logsig_f(zu)+logsig_f(-zu))*m + y0 - (al0+al1)*m;
  int tid = threadIdx.x;
  red[tid] = contrib;
  __syncthreads();
  for (int o=128;o>0;o>>=1){ if (tid<o) red[tid]+=red[tid+o]; __syncthreads(); }
  if (tid==0) atomicAdd(acc+b, red[0]);
}

// ---------------- final 0.5(log2pi + z^2) sum ----------------
__global__ __launch_bounds__(256) void final_post_k(
    const float* __restrict__ z, const float* __restrict__ mask, float* __restrict__ acc){
  __shared__ float red[256];
  int b = blockIdx.y; int t = blockIdx.x*256 + threadIdx.x;
  float m = mask[(size_t)b*TTT + t];
  float z0 = z[((size_t)b*2+0)*TTT + t];
  float z1 = z[((size_t)b*2+1)*TTT + t];
  float contrib = 0.5f*(LOG2PI_F + z0*z0)*m + 0.5f*(LOG2PI_F + z1*z1)*m;
  int tid = threadIdx.x;
  red[tid] = contrib;
  __syncthreads();
  for (int o=128;o>0;o>>=1){ if (tid<o) red[tid]+=red[tid+o]; __syncthreads(); }
  if (tid==0) atomicAdd(acc+b, red[0]);
}

__global__ void write_out_k(const float* __restrict__ acc, float* __restrict__ out, int n){
  int i = threadIdx.x;
  if (i < n) out[i] = acc[i];
}

extern "C" void kernel_launch(void* const* d_in, const int* in_sizes, int n_in,
                              void* d_out, int out_size, void* d_ws, size_t ws_size,
                              hipStream_t stream){
  (void)n_in; (void)out_size; (void)ws_size;
  const float* x         = (const float*)d_in[0];
  const float* mask      = (const float*)d_in[1];
  const float* w_in      = (const float*)d_in[2];
  const float* e_q       = (const float*)d_in[3];
  const float* pre_w     = (const float*)d_in[4];
  const float* pre_b     = (const float*)d_in[5];
  const float* proj_w    = (const float*)d_in[6];
  const float* proj_b    = (const float*)d_in[7];
  const float* dds_dep_w = (const float*)d_in[8];
  const float* dds_dep_b = (const float*)d_in[9];
  const float* dds_pw_w  = (const float*)d_in[10];
  const float* dds_pw_b  = (const float*)d_in[11];
  const float* dds_ln_g  = (const float*)d_in[12];
  const float* dds_ln_b  = (const float*)d_in[13];
  const float* post_pre_w  = (const float*)d_in[14];
  const float* post_pre_b  = (const float*)d_in[15];
  const float* post_proj_w = (const float*)d_in[16];
  const float* post_proj_b = (const float*)d_in[17];
  const float* pdds_dep_w  = (const float*)d_in[18];
  const float* pdds_dep_b  = (const float*)d_in[19];
  const float* pdds_pw_w   = (const float*)d_in[20];
  const float* pdds_pw_b   = (const float*)d_in[21];
  const float* pdds_ln_g   = (const float*)d_in[22];
  const float* pdds_ln_b   = (const float*)d_in[23];
  const float* aff_m    = (const float*)d_in[24];
  const float* aff_logs = (const float*)d_in[25];
  const float* f_pre_w  = (const float*)d_in[26];
  const float* f_pre_b  = (const float*)d_in[27];
  const float* f_dep_w  = (const float*)d_in[28];
  const float* f_dep_b  = (const float*)d_in[29];
  const float* f_pw_w   = (const float*)d_in[30];
  const float* f_pw_b   = (const float*)d_in[31];
  const float* f_ln_g   = (const float*)d_in[32];
  const float* f_ln_b   = (const float*)d_in[33];
  const float* f_proj_w = (const float*)d_in[34];
  const float* f_proj_b = (const float*)d_in[35];
  const float* paff_m    = (const float*)d_in[36];
  const float* paff_logs = (const float*)d_in[37];
  const float* p_pre_w  = (const float*)d_in[38];
  const float* p_pre_b  = (const float*)d_in[39];
  const float* p_dep_w  = (const float*)d_in[40];
  const float* p_dep_b  = (const float*)d_in[41];
  const float* p_pw_w   = (const float*)d_in[42];
  const float* p_pw_b   = (const float*)d_in[43];
  const float* p_ln_g   = (const float*)d_in[44];
  const float* p_ln_b   = (const float*)d_in[45];
  const float* p_proj_w = (const float*)d_in[46];
  const float* p_proj_b = (const float*)d_in[47];

  int Bn = in_sizes[0] / (CC*TTT);
  size_t big2 = (size_t)Bn*CC*TTT;
  unsigned short* xT = (unsigned short*)d_ws;
  unsigned short* A  = xT + big2;
  unsigned short* Bb = A  + big2;
  unsigned short* H  = Bb + big2;
  unsigned short* GP = H  + big2;
  unsigned short* Wb = GP + big2;
  size_t wtot = 33*(size_t)WSLOT + 8*(size_t)PSW;
  float* parP = (float*)(Wb + ((wtot + 7) & ~(size_t)7));
  float* zbuf = parP + 30*(size_t)PARL;
  float* acc  = zbuf + (size_t)Bn*2*TTT;

  hipMemsetAsync(acc, 0, Bn*sizeof(float), stream);
  convert_w_k<<<(int)((wtot + 255)/256), 256, 0, stream>>>(
      pre_w, proj_w, post_proj_w, dds_pw_w, pdds_pw_w, p_pw_w, f_pw_w,
      p_proj_w, f_proj_w, Wb);
  pack_par_k<<<(30*PARL + 255)/256, 256, 0, stream>>>(
      dds_dep_w, dds_dep_b, dds_ln_g, dds_ln_b, dds_pw_b,
      pdds_dep_w, pdds_dep_b, pdds_ln_g, pdds_ln_b, pdds_pw_b,
      p_dep_w, p_dep_b, p_ln_g, p_ln_b, p_pw_b,
      f_dep_w, f_dep_b, f_ln_g, f_ln_b, f_pw_b, parP);

  dim3 g32(TTT/32, Bn), g256(TTT/256, Bn);
  dim3 b256(256);

  unsigned short* W_pre      = Wb + 0*(size_t)WSLOT;
  unsigned short* W_proj     = Wb + 1*(size_t)WSLOT;
  unsigned short* W_postproj = Wb + 2*(size_t)WSLOT;
  unsigned short* W_dds      = Wb + 3*(size_t)WSLOT;
  unsigned short* W_pdds     = Wb + 6*(size_t)WSLOT;
  unsigned short* W_ppw      = Wb + 9*(size_t)WSLOT;
  unsigned short* W_fpw      = Wb + 21*(size_t)WSLOT;
  unsigned short* W_pproj    = Wb + 33*(size_t)WSLOT;
  unsigned short* W_fproj    = W_pproj + 4*(size_t)PSW;

  transpose_x_k<<<g32, b256, 0, stream>>>(x, xT);

  // ---- h path (param set 0) ----
  conv_cc_k<<<g32, b256, 0, stream>>>(xT, W_pre, pre_b, mask, nullptr, A, 0);
  mega_dds_k<<<g32, b256, 0, stream>>>(A, nullptr, 0, nullptr, Bb, mask,
      parP + 0*(size_t)3*PARL, nullptr, nullptr,
      W_dds, 0, 0, nullptr, nullptr, nullptr, 0, acc);
  conv_cc_k<<<g32, b256, 0, stream>>>(Bb, W_proj, proj_b, mask, nullptr, H, 1);

  // ---- hw path (param set 1) ----
  mega_dds_k<<<g32, b256, 0, stream>>>(nullptr, w_in, TTT, nullptr, A, mask,
      parP + 1*(size_t)3*PARL, post_pre_w, post_pre_b,
      W_pdds, 1, 0, nullptr, nullptr, nullptr, 0, acc);
  conv_cc_k<<<g32, b256, 0, stream>>>(A, W_postproj, post_proj_b, mask, H, GP, 2);

  // ---- init z ----
  init_z_k<<<g256, b256, 0, stream>>>(e_q, mask, paff_m, paff_logs, zbuf, acc);

  // ---- 4 posterior flows (g = GP, param sets 2..5) ----
  for (int f=0; f<4; f++){
    int s = f & 1;
    mega_dds_k<<<g32, b256, 0, stream>>>(nullptr, zbuf + (size_t)s*TTT, 2*TTT, GP, nullptr, mask,
        parP + (size_t)(2+f)*3*PARL,
        p_pre_w + (size_t)f*CC, p_pre_b + (size_t)f*CC,
        W_ppw + (size_t)f*3*WSLOT, 1, 1,
        W_pproj + (size_t)f*PSW, p_proj_b + (size_t)f*PP, zbuf, s, acc);
  }

  // ---- transition ----
  final_pre_k<<<g256, b256, 0, stream>>>(zbuf, w_in, mask, aff_m, aff_logs, acc);

  // ---- 4 flows (g = H, param sets 6..9) ----
  for (int f=0; f<4; f++){
    int s = f & 1;
    mega_dds_k<<<g32, b256, 0, stream>>>(nullptr, zbuf + (size_t)s*TTT, 2*TTT, H, nullptr, mask,
        parP + (size_t)(6+f)*3*PARL,
        f_pre_w + (size_t)f*CC, f_pre_b + (size_t)f*CC,
        W_fpw + (size_t)f*3*WSLOT, 1, 1,
        W_fproj + (size_t)f*PSW, f_proj_b + (size_t)f*PP, zbuf, s, acc);
  }

  final_post_k<<<g256, b256, 0, stream>>>(zbuf, mask, acc);
  write_out_k<<<1, 64, 0, stream>>>(acc, (float*)d_out, Bn);
}